// Round 6
// baseline (1018.684 us; speedup 1.0000x reference)
//
#include <hip/hip_runtime.h>
#include <hip/hip_bf16.h>
#include <hip/hip_fp16.h>
#include <math.h>

#define N_NODES 20000
#define M_PAD 20096   // 314 * 64
#define N_EDGES 320000
#define N_GRAPHS 8

typedef _Float16 half8 __attribute__((ext_vector_type(8)));
typedef float floatx4 __attribute__((ext_vector_type(4)));

struct h4pack { __half2 a, b; }; // 8B, 16B-unaligned-safe 4x fp16

__device__ __forceinline__ float leaky02(float x) { return x > 0.f ? x : 0.2f * x; }
__device__ __forceinline__ float sel4(int hl, float a, float b, float c, float d) {
    return hl < 2 ? (hl == 0 ? a : b) : (hl == 2 ? c : d);
}

// ---------------- encoder: x[N,5] -> relu -> [N,64] -> relu -> [N,128] (fp16 out) --------
__global__ void encoder_kernel(const float* __restrict__ x,
                               const float* __restrict__ w1, const float* __restrict__ b1,
                               const float* __restrict__ w2, const float* __restrict__ b2,
                               __half* __restrict__ out) {
    const int n0 = blockIdx.x * 8;
    const int tid = threadIdx.x; // 128
    __shared__ float s_x[8][5];
    __shared__ float s_h1[8][64];
    if (tid < 40) s_x[tid / 5][tid % 5] = x[(size_t)(n0 + tid / 5) * 5 + (tid % 5)];
    __syncthreads();
    if (tid < 64) {
        #pragma unroll
        for (int n = 0; n < 8; ++n) {
            float a = b1[tid];
            #pragma unroll
            for (int k = 0; k < 5; ++k) a += s_x[n][k] * w1[k * 64 + tid];
            s_h1[n][tid] = fmaxf(a, 0.f);
        }
    }
    __syncthreads();
    float acc[8];
    #pragma unroll
    for (int n = 0; n < 8; ++n) acc[n] = b2[tid];
    for (int k = 0; k < 64; ++k) {
        float wv = w2[k * 128 + tid];
        #pragma unroll
        for (int n = 0; n < 8; ++n) acc[n] += s_h1[n][k] * wv;
    }
    #pragma unroll
    for (int n = 0; n < 8; ++n)
        out[(size_t)(n0 + n) * 128 + tid] = __float2half(fmaxf(acc[n], 0.f));
}

// ---------------- prep: edge_attr sum + per-dst degree count (fused) ----------------
__global__ void prep_kernel(const float* __restrict__ ea, const int* __restrict__ dst,
                            float* __restrict__ ea_sum, int* __restrict__ cnt) {
    const int tid = threadIdx.x;
    float a0 = 0, a1 = 0, a2 = 0, a3 = 0;
    for (int i = blockIdx.x * blockDim.x + tid; i < N_EDGES; i += gridDim.x * blockDim.x) {
        float4 v = ((const float4*)ea)[i];
        a0 += v.x; a1 += v.y; a2 += v.z; a3 += v.w;
        atomicAdd(&cnt[dst[i]], 1);
    }
    #pragma unroll
    for (int off = 32; off; off >>= 1) {
        a0 += __shfl_down(a0, off, 64);
        a1 += __shfl_down(a1, off, 64);
        a2 += __shfl_down(a2, off, 64);
        a3 += __shfl_down(a3, off, 64);
    }
    __shared__ float s[4][4];
    const int wave = tid >> 6, lane = tid & 63;
    if (lane == 0) { s[wave][0] = a0; s[wave][1] = a1; s[wave][2] = a2; s[wave][3] = a3; }
    __syncthreads();
    if (tid < 4) {
        float t = s[0][tid] + s[1][tid] + s[2][tid] + s[3][tid];
        atomicAdd(&ea_sum[tid], t);
    }
}

__global__ void scan_kernel(const int* __restrict__ cnt, int* __restrict__ row_ptr) {
    __shared__ int s_sum[1024];
    const int tid = threadIdx.x;
    int local[20];
    int run = 0;
    const int base = tid * 20;
    #pragma unroll
    for (int i = 0; i < 20; ++i) {
        int idx = base + i;
        int v = (idx < N_NODES) ? cnt[idx] : 0;
        run += v;
        local[i] = run;
    }
    s_sum[tid] = run;
    __syncthreads();
    for (int off = 1; off < 1024; off <<= 1) {
        int v = (tid >= off) ? s_sum[tid - off] : 0;
        __syncthreads();
        s_sum[tid] += v;
        __syncthreads();
    }
    const int prev = (tid > 0) ? s_sum[tid - 1] : 0;
    #pragma unroll
    for (int i = 0; i < 20; ++i) {
        int idx = base + i;
        if (idx < N_NODES) row_ptr[idx + 1] = prev + local[i];
    }
    if (tid == 0) row_ptr[0] = 0;
}

// direct scatter: write (src, ea) payloads straight into CSR slots
__global__ void scatter_kernel(const int* __restrict__ src, const int* __restrict__ dst,
                               const float* __restrict__ ea,
                               const int* __restrict__ row_ptr, int* __restrict__ cur,
                               int* __restrict__ csr_src, float* __restrict__ csr_ea) {
    int i = blockIdx.x * 256 + threadIdx.x;
    if (i < N_EDGES) {
        int d = dst[i];
        int p = atomicAdd(&cur[d], 1);
        int idx = row_ptr[d] + p;
        csr_src[idx] = src[i];
        ((float4*)csr_ea)[idx] = ((const float4*)ea)[i];
    }
}

// ---------------- weight convert+transpose, all 3 layers in one launch ----------------
__global__ void wconv_all_kernel(const float* __restrict__ w1, const float* __restrict__ w2,
                                 const float* __restrict__ w3,
                                 __half* __restrict__ wt1, __half* __restrict__ wt2,
                                 __half* __restrict__ wt3) {
    int i = blockIdx.x * 256 + threadIdx.x;
    if (i < 32768) {                       // g1: K=128, N=256
        int k = i >> 8, n = i & 255;
        wt1[(size_t)n * 128 + k] = __float2half(w1[i]);
    } else if (i < 98304) {                // g2: K=256, N=256
        int j = i - 32768;
        int k = j >> 8, n = j & 255;
        wt2[(size_t)n * 256 + k] = __float2half(w2[j]);
    } else if (i < 114688) {               // g3: K=256, N=64
        int j = i - 98304;
        int k = j >> 6, n = j & 63;
        wt3[(size_t)n * 256 + k] = __float2half(w3[j]);
    }
}

// ---------------- vtab + self-loop a_e for all 3 layers (block = layer) ----------------
__global__ void vtab_all_kernel(const float* __restrict__ we1, const float* __restrict__ ae1,
                                const float* __restrict__ we2, const float* __restrict__ ae2,
                                const float* __restrict__ we3, const float* __restrict__ ae3,
                                const float* __restrict__ ea_sum,
                                float* __restrict__ vtab, float* __restrict__ lpae) {
    const int L = blockIdx.x;
    const float* We = (L == 0) ? we1 : ((L == 1) ? we2 : we3);
    const float* Ae = (L == 0) ? ae1 : ((L == 1) ? ae2 : ae3);
    const int H = (L < 2) ? 4 : 1;
    const int tid = threadIdx.x; // 64
    __shared__ float s_v[16];
    if (tid < 4 * H) {
        const int k = tid / H, h = tid % H;
        float v = 0.f;
        for (int c = 0; c < 64; ++c) v += We[k * (H * 64) + h * 64 + c] * Ae[h * 64 + c];
        vtab[L * 16 + k * 4 + h] = v;
        s_v[k * 4 + h] = v;
    }
    __syncthreads();
    if (tid < H) {
        const float inv = 1.0f / (float)N_EDGES;
        float l = 0.f;
        #pragma unroll
        for (int k = 0; k < 4; ++k) l += ea_sum[k] * inv * s_v[k * 4 + tid];
        lpae[L * 4 + tid] = l;
    }
}

// ---------------- MFMA GEMM + fused attention scalars (K-step 64) ----------------
template<int N, int H>
__global__ __launch_bounds__(256) void mgemm_kernel(
    const __half* __restrict__ X, const __half* __restrict__ Wt,
    const float* __restrict__ asrc, const float* __restrict__ adst,
    __half* __restrict__ Y, float* __restrict__ a_s, float* __restrict__ a_d, int K) {
    constexpr int STR = 72;
    __shared__ _Float16 sX[64 * STR];
    __shared__ _Float16 sW[64 * STR];
    const int tid = threadIdx.x;
    const int lane = tid & 63, w = tid >> 6;
    const int l16 = lane & 15, kg = lane >> 4;
    const int n0 = blockIdx.x * 64;
    const int c0 = blockIdx.y * 64;
    const int by = blockIdx.y;

    floatx4 acc[4];
    #pragma unroll
    for (int ct = 0; ct < 4; ++ct) acc[ct] = (floatx4){0.f, 0.f, 0.f, 0.f};

    const int srow = tid >> 2, sseg = tid & 3;
    for (int k0 = 0; k0 < K; k0 += 64) {
        float4 xv0 = *(const float4*)(X + (size_t)(n0 + srow) * K + k0 + sseg * 8);
        float4 xv1 = *(const float4*)(X + (size_t)(n0 + srow) * K + k0 + 32 + sseg * 8);
        float4 wv0 = *(const float4*)(Wt + (size_t)(c0 + srow) * K + k0 + sseg * 8);
        float4 wv1 = *(const float4*)(Wt + (size_t)(c0 + srow) * K + k0 + 32 + sseg * 8);
        __syncthreads();
        *(float4*)&sX[srow * STR + sseg * 8] = xv0;
        *(float4*)&sX[srow * STR + 32 + sseg * 8] = xv1;
        *(float4*)&sW[srow * STR + sseg * 8] = wv0;
        *(float4*)&sW[srow * STR + 32 + sseg * 8] = wv1;
        __syncthreads();
        #pragma unroll
        for (int ks = 0; ks < 2; ++ks) {
            half8 a = *(const half8*)&sX[(w * 16 + l16) * STR + ks * 32 + kg * 8];
            #pragma unroll
            for (int ct = 0; ct < 4; ++ct) {
                half8 b = *(const half8*)&sW[(ct * 16 + l16) * STR + ks * 32 + kg * 8];
                acc[ct] = __builtin_amdgcn_mfma_f32_16x16x32_f16(a, b, acc[ct], 0, 0, 0);
            }
        }
    }

    // epilogue: C/D layout col = lane&15, row = (lane>>4)*4 + reg
    const int rowb = n0 + w * 16 + kg * 4;
    float ar[4], ad4[4];
    #pragma unroll
    for (int ct = 0; ct < 4; ++ct) {
        ar[ct] = asrc[c0 + ct * 16 + l16];
        ad4[ct] = adst[c0 + ct * 16 + l16];
    }
    #pragma unroll
    for (int ct = 0; ct < 4; ++ct) {
        const int col = c0 + ct * 16 + l16;
        #pragma unroll
        for (int r = 0; r < 4; ++r)
            Y[(size_t)(rowb + r) * N + col] = __float2half(acc[ct][r]);
    }
    #pragma unroll
    for (int r = 0; r < 4; ++r) {
        float p = acc[0][r] * ar[0] + acc[1][r] * ar[1] + acc[2][r] * ar[2] + acc[3][r] * ar[3];
        float q = acc[0][r] * ad4[0] + acc[1][r] * ad4[1] + acc[2][r] * ad4[2] + acc[3][r] * ad4[3];
        #pragma unroll
        for (int off = 1; off < 16; off <<= 1) {
            p += __shfl_xor(p, off, 64);
            q += __shfl_xor(q, off, 64);
        }
        if (l16 == 0) {
            const int node = rowb + r;
            a_s[(size_t)node * H + by] = p;
            a_d[(size_t)node * H + by] = q;
        }
    }
}

// ---------------- GAT aggregation: wave per node, self-logit-shifted softmax ----------------
// Softmax shifted by the self-loop logit (exact in exact arithmetic; logit spread is O(1)
// for 0.1-scale weights, far inside expf range). exp computed once per edge-head on the
// producer lane; inner step is shfl-broadcast + gather + fma only.
template<int H, int HC, bool ELU>
__global__ __launch_bounds__(256) void agg4_kernel(
    const __half* __restrict__ hh,
    const float* __restrict__ a_s, const float* __restrict__ a_d,
    const float* __restrict__ vtab, const float* __restrict__ lpae,
    const int* __restrict__ csr_src, const float* __restrict__ csr_ea,
    const int* __restrict__ row_ptr, const float* __restrict__ bias,
    __half* __restrict__ out) {
    constexpr int CPT = HC / 64;
    const int wave = threadIdx.x >> 6;
    const int lane = threadIdx.x & 63;
    const int d = blockIdx.x * 4 + wave;

    const int base = row_ptr[d], end = row_ptr[d + 1];
    const int colbase = lane * CPT;
    const int hl = (H == 1) ? 0 : (colbase >> 6);

    float vt[4][H];
    #pragma unroll
    for (int k = 0; k < 4; ++k)
        #pragma unroll
        for (int h = 0; h < H; ++h) vt[k][h] = vtab[k * 4 + h];

    float add_[H], lself[H];
    if (H == 4) {
        float4 t = *(const float4*)&a_d[(size_t)d * 4];
        add_[0] = t.x; add_[1] = t.y; add_[2] = t.z; add_[3] = t.w;
        float4 s4 = *(const float4*)&a_s[(size_t)d * 4];
        lself[0] = leaky02(s4.x + add_[0] + lpae[0]);
        lself[1] = leaky02(s4.y + add_[1] + lpae[1]);
        lself[2] = leaky02(s4.z + add_[2] + lpae[2]);
        lself[3] = leaky02(s4.w + add_[3] + lpae[3]);
    } else {
        add_[0] = a_d[d];
        lself[0] = leaky02(a_s[d] + add_[0] + lpae[0]);
    }

    // self-loop term: w_self = exp(lself - lself) = 1
    float zacc = 1.f;
    float acc[CPT];
    if (CPT == 4) {
        h4pack hv = *(const h4pack*)(hh + (size_t)d * HC + colbase);
        float2 f0 = __half22float2(hv.a);
        float2 f1 = __half22float2(hv.b);
        acc[0] = f0.x; acc[1] = f0.y; acc[2] = f1.x; acc[3] = f1.y;
    } else {
        acc[0] = __half2float(hh[(size_t)d * HC + colbase]);
    }

#define EDGE_STEP(tt) { \
        int s_ = __shfl(my_s, (tt), 64); \
        float w_; \
        if (H == 4) { \
            float t0 = __shfl(w0, (tt), 64), t1 = __shfl(w1, (tt), 64); \
            float t2 = __shfl(w2, (tt), 64), t3 = __shfl(w3, (tt), 64); \
            w_ = sel4(hl, t0, t1, t2, t3); \
        } else { \
            w_ = __shfl(w0, (tt), 64); \
        } \
        if (CPT == 4) { \
            h4pack hv_ = *(const h4pack*)(hh + (size_t)s_ * HC + colbase); \
            float2 f0_ = __half22float2(hv_.a); \
            float2 f1_ = __half22float2(hv_.b); \
            acc[0] += w_ * f0_.x; acc[1] += w_ * f0_.y; \
            acc[2] += w_ * f1_.x; acc[3] += w_ * f1_.y; \
        } else { \
            acc[0] += w_ * __half2float(hh[(size_t)s_ * HC + colbase]); \
        } \
        zacc += w_; }

    for (int c0 = base; c0 < end; c0 += 64) {
        const int nc = min(64, end - c0);
        int my_s = 0;
        float w0 = 0.f, w1 = 0.f, w2 = 0.f, w3 = 0.f;
        if (lane < nc) {
            my_s = csr_src[c0 + lane];
            float4 eav = ((const float4*)csr_ea)[c0 + lane];
            if (H == 4) {
                float4 as4 = *(const float4*)&a_s[(size_t)my_s * 4];
                float l0 = leaky02(as4.x + add_[0] + eav.x * vt[0][0] + eav.y * vt[1][0] + eav.z * vt[2][0] + eav.w * vt[3][0]);
                float l1 = leaky02(as4.y + add_[1] + eav.x * vt[0][1] + eav.y * vt[1][1] + eav.z * vt[2][1] + eav.w * vt[3][1]);
                float l2 = leaky02(as4.z + add_[2] + eav.x * vt[0][2] + eav.y * vt[1][2] + eav.z * vt[2][2] + eav.w * vt[3][2]);
                float l3 = leaky02(as4.w + add_[3] + eav.x * vt[0][3] + eav.y * vt[1][3] + eav.z * vt[2][3] + eav.w * vt[3][3]);
                w0 = __expf(l0 - lself[0]);
                w1 = __expf(l1 - lself[1]);
                w2 = __expf(l2 - lself[2]);
                w3 = __expf(l3 - lself[3]);
            } else {
                float l0 = leaky02(a_s[my_s] + add_[0] + eav.x * vt[0][0] + eav.y * vt[1][0] + eav.z * vt[2][0] + eav.w * vt[3][0]);
                w0 = __expf(l0 - lself[0]);
            }
        }
        int t = 0;
        for (; t + 8 <= nc; t += 8) {
            EDGE_STEP(t)
            EDGE_STEP(t + 1)
            EDGE_STEP(t + 2)
            EDGE_STEP(t + 3)
            EDGE_STEP(t + 4)
            EDGE_STEP(t + 5)
            EDGE_STEP(t + 6)
            EDGE_STEP(t + 7)
        }
        for (; t < nc; ++t) {
            EDGE_STEP(t)
        }
    }
#undef EDGE_STEP

    const float invz = 1.f / (zacc + 1e-16f);
    #pragma unroll
    for (int c = 0; c < CPT; ++c) {
        float v = acc[c] * invz + bias[colbase + c];
        if (ELU) v = (v > 0.f) ? v : (__expf(v) - 1.f);
        acc[c] = v;
    }
    if (CPT == 4) {
        __half2* op = (__half2*)(out + (size_t)d * HC + colbase);
        op[0] = __floats2half2_rn(acc[0], acc[1]);
        op[1] = __floats2half2_rn(acc[2], acc[3]);
    } else {
        out[(size_t)d * HC + colbase] = __float2half(acc[0]);
    }
}

// ---------------- global mean pool (hierarchical, fp16 in) ----------------
__global__ void pool_kernel(const __half* __restrict__ h3, const int* __restrict__ batch,
                            float* __restrict__ psum, float* __restrict__ pcnt) {
    __shared__ float s_acc[8][64];
    __shared__ float s_cnt[8];
    const int tid = threadIdx.x; // 256
    for (int i = tid; i < 512; i += 256) s_acc[i >> 6][i & 63] = 0.f;
    if (tid < 8) s_cnt[tid] = 0.f;
    __syncthreads();
    const int col = tid & 63, nl = tid >> 6;
    const int n0 = blockIdx.x * 64;
    for (int nn = nl; nn < 64; nn += 4) {
        int n = n0 + nn;
        if (n < N_NODES) {
            int b = batch[n];
            atomicAdd(&s_acc[b][col], __half2float(h3[(size_t)n * 64 + col]));
            if (col == 0) atomicAdd(&s_cnt[b], 1.0f);
        }
    }
    __syncthreads();
    for (int i = tid; i < 512; i += 256) {
        float v = s_acc[i >> 6][i & 63];
        if (v != 0.f) atomicAdd(&psum[i], v);
    }
    if (tid < 8 && s_cnt[tid] > 0.f) atomicAdd(&pcnt[tid], s_cnt[tid]);
}

// ---------------- head part 1: static_features ----------------
__global__ void head_sf_kernel(const float* __restrict__ psum, const float* __restrict__ pcnt,
                               const float* __restrict__ w1, const float* __restrict__ b1,
                               const float* __restrict__ w2, const float* __restrict__ b2,
                               float* __restrict__ out) {
    const int b = blockIdx.y;
    const int c0 = blockIdx.x * 128;
    const int tid = threadIdx.x; // 128
    __shared__ float s_g[64];
    __shared__ float s_p1[128];
    if (tid < 64) {
        float c = pcnt[b];
        c = (c < 1.f) ? 1.f : c;
        s_g[tid] = psum[b * 64 + tid] / c;
    }
    __syncthreads();
    {
        float a = b1[tid];
        #pragma unroll 8
        for (int k = 0; k < 64; ++k) a += s_g[k] * w1[k * 128 + tid];
        s_p1[tid] = fmaxf(a, 0.f);
    }
    __syncthreads();
    const int col = c0 + tid;
    float a = b2[col];
    #pragma unroll 8
    for (int k = 0; k < 128; ++k) a += s_p1[k] * w2[k * 768 + col];
    out[b * 768 + col] = a;
}

// ---------------- head part 2: vulnerability scores ----------------
__global__ void scores_kernel(const float* __restrict__ sf,
                              const float* __restrict__ vw, const float* __restrict__ vb,
                              float* __restrict__ out) {
    const int b = blockIdx.x;
    const int tid = threadIdx.x; // 256
    const int wave = tid >> 6, lane = tid & 63;
    float part[5] = {0.f, 0.f, 0.f, 0.f, 0.f};
    for (int k = tid; k < 768; k += 256) {
        float s = sf[b * 768 + k];
        #pragma unroll
        for (int v = 0; v < 5; ++v) part[v] += s * vw[k * 5 + v];
    }
    #pragma unroll
    for (int v = 0; v < 5; ++v)
        #pragma unroll
        for (int off = 32; off; off >>= 1) part[v] += __shfl_down(part[v], off, 64);
    __shared__ float sred[4][5];
    if (lane == 0) {
        #pragma unroll
        for (int v = 0; v < 5; ++v) sred[wave][v] = part[v];
    }
    __syncthreads();
    if (tid < 5) {
        float a = vb[tid] + sred[0][tid] + sred[1][tid] + sred[2][tid] + sred[3][tid];
        out[6144 + b * 5 + tid] = 1.f / (1.f + __expf(-a));
    }
}

extern "C" void kernel_launch(void* const* d_in, const int* in_sizes, int n_in,
                              void* d_out, int out_size, void* d_ws, size_t ws_size,
                              hipStream_t stream) {
    const float* x       = (const float*)d_in[0];
    const int*   eidx    = (const int*)d_in[1];
    const float* ea      = (const float*)d_in[2];
    const int*   batch   = (const int*)d_in[3];
    const float* enc_w1  = (const float*)d_in[4];
    const float* enc_b1  = (const float*)d_in[5];
    const float* enc_w2  = (const float*)d_in[6];
    const float* enc_b2  = (const float*)d_in[7];
    const float* g1_w    = (const float*)d_in[8];
    const float* g1_asrc = (const float*)d_in[9];
    const float* g1_adst = (const float*)d_in[10];
    const float* g1_we   = (const float*)d_in[11];
    const float* g1_ae   = (const float*)d_in[12];
    const float* g1_b    = (const float*)d_in[13];
    const float* g2_w    = (const float*)d_in[14];
    const float* g2_asrc = (const float*)d_in[15];
    const float* g2_adst = (const float*)d_in[16];
    const float* g2_we   = (const float*)d_in[17];
    const float* g2_ae   = (const float*)d_in[18];
    const float* g2_b    = (const float*)d_in[19];
    const float* g3_w    = (const float*)d_in[20];
    const float* g3_asrc = (const float*)d_in[21];
    const float* g3_adst = (const float*)d_in[22];
    const float* g3_we   = (const float*)d_in[23];
    const float* g3_ae   = (const float*)d_in[24];
    const float* g3_b    = (const float*)d_in[25];
    const float* pw1     = (const float*)d_in[26];
    const float* pb1     = (const float*)d_in[27];
    const float* pw2     = (const float*)d_in[28];
    const float* pb2     = (const float*)d_in[29];
    const float* vw      = (const float*)d_in[30];
    const float* vb      = (const float*)d_in[31];

    const int* src = eidx;
    const int* dst = eidx + N_EDGES;

    // ---- workspace layout ----
    __half* h16a = (__half*)d_ws;                           // [M_PAD][256] f16
    __half* h16b = h16a + (size_t)M_PAD * 256;              // [M_PAD][256] f16
    __half* hh16 = h16b + (size_t)M_PAD * 256;              // [M_PAD][256] f16
    __half* wt1  = hh16 + (size_t)M_PAD * 256;              // [256][128]
    __half* wt2  = wt1 + 32768;                             // [256][256]
    __half* wt3  = wt2 + 65536;                             // [64][256]
    float* asb   = (float*)(wt3 + 16384);                   // [M_PAD][4]
    float* adb   = asb + (size_t)M_PAD * 4;                 // [M_PAD][4]
    float* zreg  = adb + (size_t)M_PAD * 4;
    float* ea_sum = zreg;                                   // 4
    float* psum   = zreg + 4;                               // 512
    float* pcnt   = zreg + 516;                             // 8
    float* vtab   = zreg + 524;                             // 3*16
    float* lpae   = zreg + 572;                             // 3*4
    int* icnt    = (int*)(zreg + 584);                      // N
    int* icur    = icnt + N_NODES;                          // N
    int* irow    = icur + N_NODES;                          // N+16
    int* csr_src = irow + N_NODES + 16;                     // E
    float* csr_ea = (float*)(csr_src + N_EDGES);            // E*4 (16B aligned)

    hipMemsetAsync(zreg, 0, 584 * sizeof(float), stream);
    hipMemsetAsync(icnt, 0, 2 * N_NODES * sizeof(int), stream);

    prep_kernel<<<256, 256, 0, stream>>>(ea, dst, ea_sum, icnt);
    encoder_kernel<<<N_NODES / 8, 128, 0, stream>>>(x, enc_w1, enc_b1, enc_w2, enc_b2, h16a);
    scan_kernel<<<1, 1024, 0, stream>>>(icnt, irow);
    scatter_kernel<<<(N_EDGES + 255) / 256, 256, 0, stream>>>(src, dst, ea, irow, icur, csr_src, csr_ea);
    wconv_all_kernel<<<448, 256, 0, stream>>>(g1_w, g2_w, g3_w, wt1, wt2, wt3);
    vtab_all_kernel<<<3, 64, 0, stream>>>(g1_we, g1_ae, g2_we, g2_ae, g3_we, g3_ae, ea_sum, vtab, lpae);

    // layer 1: K=128 -> HC=256, H=4, ELU      (h16a -> hh16 -> h16b)
    mgemm_kernel<256, 4><<<dim3(M_PAD / 64, 4), 256, 0, stream>>>(h16a, wt1, g1_asrc, g1_adst, hh16, asb, adb, 128);
    agg4_kernel<4, 256, true><<<N_NODES / 4, 256, 0, stream>>>(hh16, asb, adb, vtab, lpae, csr_src, csr_ea, irow, g1_b, h16b);

    // layer 2: K=256 -> HC=256, H=4, ELU      (h16b -> hh16 -> h16a)
    mgemm_kernel<256, 4><<<dim3(M_PAD / 64, 4), 256, 0, stream>>>(h16b, wt2, g2_asrc, g2_adst, hh16, asb, adb, 256);
    agg4_kernel<4, 256, true><<<N_NODES / 4, 256, 0, stream>>>(hh16, asb, adb, vtab + 16, lpae + 4, csr_src, csr_ea, irow, g2_b, h16a);

    // layer 3: K=256 -> HC=64, H=1, no ELU    (h16a -> hh16 -> h16b)
    mgemm_kernel<64, 1><<<dim3(M_PAD / 64, 1), 256, 0, stream>>>(h16a, wt3, g3_asrc, g3_adst, hh16, asb, adb, 256);
    agg4_kernel<1, 64, false><<<N_NODES / 4, 256, 0, stream>>>(hh16, asb, adb, vtab + 32, lpae + 8, csr_src, csr_ea, irow, g3_b, h16b);

    pool_kernel<<<(N_NODES + 63) / 64, 256, 0, stream>>>(h16b, batch, psum, pcnt);
    head_sf_kernel<<<dim3(6, 8), 128, 0, stream>>>(psum, pcnt, pw1, pb1, pw2, pb2, (float*)d_out);
    scores_kernel<<<8, 256, 0, stream>>>((float*)d_out, vw, vb, (float*)d_out);
}

// Round 7
// 321.722 us; speedup vs baseline: 3.1663x; 3.1663x over previous
//
#include <hip/hip_runtime.h>
#include <hip/hip_bf16.h>
#include <hip/hip_fp16.h>
#include <math.h>

#define N_NODES 20000
#define M_PAD 20096   // 314 * 64
#define N_EDGES 320000
#define N_GRAPHS 8

typedef _Float16 half8 __attribute__((ext_vector_type(8)));
typedef float floatx4 __attribute__((ext_vector_type(4)));

struct h4pack { __half2 a, b; }; // 8B, 4x fp16

__device__ __forceinline__ float leaky02(float x) { return x > 0.f ? x : 0.2f * x; }
__device__ __forceinline__ float sel4(int hl, float a, float b, float c, float d) {
    return hl < 2 ? (hl == 0 ? a : b) : (hl == 2 ? c : d);
}

// ---------------- encoder: x[N,5] -> relu -> [N,64] -> relu -> [N,128] (fp16 out) --------
__global__ void encoder_kernel(const float* __restrict__ x,
                               const float* __restrict__ w1, const float* __restrict__ b1,
                               const float* __restrict__ w2, const float* __restrict__ b2,
                               __half* __restrict__ out) {
    const int n0 = blockIdx.x * 8;
    const int tid = threadIdx.x; // 128
    __shared__ float s_x[8][5];
    __shared__ float s_h1[8][64];
    if (tid < 40) s_x[tid / 5][tid % 5] = x[(size_t)(n0 + tid / 5) * 5 + (tid % 5)];
    __syncthreads();
    if (tid < 64) {
        #pragma unroll
        for (int n = 0; n < 8; ++n) {
            float a = b1[tid];
            #pragma unroll
            for (int k = 0; k < 5; ++k) a += s_x[n][k] * w1[k * 64 + tid];
            s_h1[n][tid] = fmaxf(a, 0.f);
        }
    }
    __syncthreads();
    float acc[8];
    #pragma unroll
    for (int n = 0; n < 8; ++n) acc[n] = b2[tid];
    for (int k = 0; k < 64; ++k) {
        float wv = w2[k * 128 + tid];
        #pragma unroll
        for (int n = 0; n < 8; ++n) acc[n] += s_h1[n][k] * wv;
    }
    #pragma unroll
    for (int n = 0; n < 8; ++n)
        out[(size_t)(n0 + n) * 128 + tid] = __float2half(fmaxf(acc[n], 0.f));
}

// ---------------- prep: edge_attr sum + per-dst degree count (fused) ----------------
__global__ void prep_kernel(const float* __restrict__ ea, const int* __restrict__ dst,
                            float* __restrict__ ea_sum, int* __restrict__ cnt) {
    const int tid = threadIdx.x;
    float a0 = 0, a1 = 0, a2 = 0, a3 = 0;
    for (int i = blockIdx.x * blockDim.x + tid; i < N_EDGES; i += gridDim.x * blockDim.x) {
        float4 v = ((const float4*)ea)[i];
        a0 += v.x; a1 += v.y; a2 += v.z; a3 += v.w;
        atomicAdd(&cnt[dst[i]], 1);
    }
    #pragma unroll
    for (int off = 32; off; off >>= 1) {
        a0 += __shfl_down(a0, off, 64);
        a1 += __shfl_down(a1, off, 64);
        a2 += __shfl_down(a2, off, 64);
        a3 += __shfl_down(a3, off, 64);
    }
    __shared__ float s[4][4];
    const int wave = tid >> 6, lane = tid & 63;
    if (lane == 0) { s[wave][0] = a0; s[wave][1] = a1; s[wave][2] = a2; s[wave][3] = a3; }
    __syncthreads();
    if (tid < 4) {
        float t = s[0][tid] + s[1][tid] + s[2][tid] + s[3][tid];
        atomicAdd(&ea_sum[tid], t);
    }
}

__global__ void scan_kernel(const int* __restrict__ cnt, int* __restrict__ row_ptr) {
    __shared__ int s_sum[1024];
    const int tid = threadIdx.x;
    int local[20];
    int run = 0;
    const int base = tid * 20;
    #pragma unroll
    for (int i = 0; i < 20; ++i) {
        int idx = base + i;
        int v = (idx < N_NODES) ? cnt[idx] : 0;
        run += v;
        local[i] = run;
    }
    s_sum[tid] = run;
    __syncthreads();
    for (int off = 1; off < 1024; off <<= 1) {
        int v = (tid >= off) ? s_sum[tid - off] : 0;
        __syncthreads();
        s_sum[tid] += v;
        __syncthreads();
    }
    const int prev = (tid > 0) ? s_sum[tid - 1] : 0;
    #pragma unroll
    for (int i = 0; i < 20; ++i) {
        int idx = base + i;
        if (idx < N_NODES) row_ptr[idx + 1] = prev + local[i];
    }
    if (tid == 0) row_ptr[0] = 0;
}

// direct scatter: write (src, ea) payloads straight into CSR slots
__global__ void scatter_kernel(const int* __restrict__ src, const int* __restrict__ dst,
                               const float* __restrict__ ea,
                               const int* __restrict__ row_ptr, int* __restrict__ cur,
                               int* __restrict__ csr_src, float* __restrict__ csr_ea) {
    int i = blockIdx.x * 256 + threadIdx.x;
    if (i < N_EDGES) {
        int d = dst[i];
        int p = atomicAdd(&cur[d], 1);
        int idx = row_ptr[d] + p;
        csr_src[idx] = src[i];
        ((float4*)csr_ea)[idx] = ((const float4*)ea)[i];
    }
}

// ---------------- const prep: weight transpose/convert (blocks 0-447) + vtab (448-450) ----
__global__ void const_prep_kernel(const float* __restrict__ w1, const float* __restrict__ w2,
                                  const float* __restrict__ w3,
                                  __half* __restrict__ wt1, __half* __restrict__ wt2,
                                  __half* __restrict__ wt3,
                                  const float* __restrict__ we1, const float* __restrict__ ae1,
                                  const float* __restrict__ we2, const float* __restrict__ ae2,
                                  const float* __restrict__ we3, const float* __restrict__ ae3,
                                  const float* __restrict__ ea_sum,
                                  float* __restrict__ vtab, float* __restrict__ lpae) {
    const int b = blockIdx.x;
    if (b < 448) {
        int i = b * 256 + threadIdx.x;
        if (i < 32768) {                       // g1: K=128, N=256
            int k = i >> 8, n = i & 255;
            wt1[(size_t)n * 128 + k] = __float2half(w1[i]);
        } else if (i < 98304) {                // g2: K=256, N=256
            int j = i - 32768;
            int k = j >> 8, n = j & 255;
            wt2[(size_t)n * 256 + k] = __float2half(w2[j]);
        } else if (i < 114688) {               // g3: K=256, N=64
            int j = i - 98304;
            int k = j >> 6, n = j & 63;
            wt3[(size_t)n * 256 + k] = __float2half(w3[j]);
        }
        return;
    }
    const int L = b - 448;
    const float* We = (L == 0) ? we1 : ((L == 1) ? we2 : we3);
    const float* Ae = (L == 0) ? ae1 : ((L == 1) ? ae2 : ae3);
    const int H = (L < 2) ? 4 : 1;
    const int tid = threadIdx.x;
    __shared__ float s_v[16];
    if (tid < 4 * H) {
        const int k = tid / H, h = tid % H;
        float v = 0.f;
        for (int c = 0; c < 64; ++c) v += We[k * (H * 64) + h * 64 + c] * Ae[h * 64 + c];
        vtab[L * 16 + k * 4 + h] = v;
        s_v[k * 4 + h] = v;
    }
    __syncthreads();
    if (tid < H) {
        const float inv = 1.0f / (float)N_EDGES;
        float l = 0.f;
        #pragma unroll
        for (int k = 0; k < 4; ++k) l += ea_sum[k] * inv * s_v[k * 4 + tid];
        lpae[L * 4 + tid] = l;
    }
}

// ---------------- MFMA GEMM + fused attention scalars (K-step 64) ----------------
template<int N, int H>
__global__ __launch_bounds__(256) void mgemm_kernel(
    const __half* __restrict__ X, const __half* __restrict__ Wt,
    const float* __restrict__ asrc, const float* __restrict__ adst,
    __half* __restrict__ Y, float* __restrict__ a_s, float* __restrict__ a_d, int K) {
    constexpr int STR = 72;
    __shared__ _Float16 sX[64 * STR];
    __shared__ _Float16 sW[64 * STR];
    const int tid = threadIdx.x;
    const int lane = tid & 63, w = tid >> 6;
    const int l16 = lane & 15, kg = lane >> 4;
    const int n0 = blockIdx.x * 64;
    const int c0 = blockIdx.y * 64;
    const int by = blockIdx.y;

    floatx4 acc[4];
    #pragma unroll
    for (int ct = 0; ct < 4; ++ct) acc[ct] = (floatx4){0.f, 0.f, 0.f, 0.f};

    const int srow = tid >> 2, sseg = tid & 3;
    for (int k0 = 0; k0 < K; k0 += 64) {
        float4 xv0 = *(const float4*)(X + (size_t)(n0 + srow) * K + k0 + sseg * 8);
        float4 xv1 = *(const float4*)(X + (size_t)(n0 + srow) * K + k0 + 32 + sseg * 8);
        float4 wv0 = *(const float4*)(Wt + (size_t)(c0 + srow) * K + k0 + sseg * 8);
        float4 wv1 = *(const float4*)(Wt + (size_t)(c0 + srow) * K + k0 + 32 + sseg * 8);
        __syncthreads();
        *(float4*)&sX[srow * STR + sseg * 8] = xv0;
        *(float4*)&sX[srow * STR + 32 + sseg * 8] = xv1;
        *(float4*)&sW[srow * STR + sseg * 8] = wv0;
        *(float4*)&sW[srow * STR + 32 + sseg * 8] = wv1;
        __syncthreads();
        #pragma unroll
        for (int ks = 0; ks < 2; ++ks) {
            half8 a = *(const half8*)&sX[(w * 16 + l16) * STR + ks * 32 + kg * 8];
            #pragma unroll
            for (int ct = 0; ct < 4; ++ct) {
                half8 b = *(const half8*)&sW[(ct * 16 + l16) * STR + ks * 32 + kg * 8];
                acc[ct] = __builtin_amdgcn_mfma_f32_16x16x32_f16(a, b, acc[ct], 0, 0, 0);
            }
        }
    }

    // epilogue: C/D layout col = lane&15, row = (lane>>4)*4 + reg
    const int rowb = n0 + w * 16 + kg * 4;
    float ar[4], ad4[4];
    #pragma unroll
    for (int ct = 0; ct < 4; ++ct) {
        ar[ct] = asrc[c0 + ct * 16 + l16];
        ad4[ct] = adst[c0 + ct * 16 + l16];
    }
    #pragma unroll
    for (int ct = 0; ct < 4; ++ct) {
        const int col = c0 + ct * 16 + l16;
        #pragma unroll
        for (int r = 0; r < 4; ++r)
            Y[(size_t)(rowb + r) * N + col] = __float2half(acc[ct][r]);
    }
    #pragma unroll
    for (int r = 0; r < 4; ++r) {
        float p = acc[0][r] * ar[0] + acc[1][r] * ar[1] + acc[2][r] * ar[2] + acc[3][r] * ar[3];
        float q = acc[0][r] * ad4[0] + acc[1][r] * ad4[1] + acc[2][r] * ad4[2] + acc[3][r] * ad4[3];
        #pragma unroll
        for (int off = 1; off < 16; off <<= 1) {
            p += __shfl_xor(p, off, 64);
            q += __shfl_xor(q, off, 64);
        }
        if (l16 == 0) {
            const int node = rowb + r;
            a_s[(size_t)node * H + by] = p;
            a_d[(size_t)node * H + by] = q;
        }
    }
}

// ---------------- GAT aggregation: wave per node, self-logit-shifted softmax ----------------
template<int H, int HC, bool ELU>
__global__ __launch_bounds__(256) void agg4_kernel(
    const __half* __restrict__ hh,
    const float* __restrict__ a_s, const float* __restrict__ a_d,
    const float* __restrict__ vtab, const float* __restrict__ lpae,
    const int* __restrict__ csr_src, const float* __restrict__ csr_ea,
    const int* __restrict__ row_ptr, const float* __restrict__ bias,
    __half* __restrict__ out) {
    constexpr int CPT = HC / 64;
    const int wave = threadIdx.x >> 6;
    const int lane = threadIdx.x & 63;
    const int d = blockIdx.x * 4 + wave;

    const int base = row_ptr[d], end = row_ptr[d + 1];
    const int colbase = lane * CPT;
    const int hl = (H == 1) ? 0 : (colbase >> 6);

    float vt[4][H];
    #pragma unroll
    for (int k = 0; k < 4; ++k)
        #pragma unroll
        for (int h = 0; h < H; ++h) vt[k][h] = vtab[k * 4 + h];

    float add_[H], lself[H];
    if (H == 4) {
        float4 t = *(const float4*)&a_d[(size_t)d * 4];
        add_[0] = t.x; add_[1] = t.y; add_[2] = t.z; add_[3] = t.w;
        float4 s4 = *(const float4*)&a_s[(size_t)d * 4];
        lself[0] = leaky02(s4.x + add_[0] + lpae[0]);
        lself[1] = leaky02(s4.y + add_[1] + lpae[1]);
        lself[2] = leaky02(s4.z + add_[2] + lpae[2]);
        lself[3] = leaky02(s4.w + add_[3] + lpae[3]);
    } else {
        add_[0] = a_d[d];
        lself[0] = leaky02(a_s[d] + add_[0] + lpae[0]);
    }

    // self-loop term: w_self = exp(lself - lself) = 1
    float zacc = 1.f;
    float acc[CPT];
    if (CPT == 4) {
        h4pack hv = *(const h4pack*)(hh + (size_t)d * HC + colbase);
        float2 f0 = __half22float2(hv.a);
        float2 f1 = __half22float2(hv.b);
        acc[0] = f0.x; acc[1] = f0.y; acc[2] = f1.x; acc[3] = f1.y;
    } else {
        acc[0] = __half2float(hh[(size_t)d * HC + colbase]);
    }

#define EDGE_STEP(tt) { \
        int s_ = __shfl(my_s, (tt), 64); \
        float w_; \
        if (H == 4) { \
            float t0 = __shfl(w0, (tt), 64), t1 = __shfl(w1, (tt), 64); \
            float t2 = __shfl(w2, (tt), 64), t3 = __shfl(w3, (tt), 64); \
            w_ = sel4(hl, t0, t1, t2, t3); \
        } else { \
            w_ = __shfl(w0, (tt), 64); \
        } \
        if (CPT == 4) { \
            h4pack hv_ = *(const h4pack*)(hh + (size_t)s_ * HC + colbase); \
            float2 f0_ = __half22float2(hv_.a); \
            float2 f1_ = __half22float2(hv_.b); \
            acc[0] += w_ * f0_.x; acc[1] += w_ * f0_.y; \
            acc[2] += w_ * f1_.x; acc[3] += w_ * f1_.y; \
        } else { \
            acc[0] += w_ * __half2float(hh[(size_t)s_ * HC + colbase]); \
        } \
        zacc += w_; }

    for (int c0 = base; c0 < end; c0 += 64) {
        const int nc = min(64, end - c0);
        int my_s = 0;
        float w0 = 0.f, w1 = 0.f, w2 = 0.f, w3 = 0.f;
        if (lane < nc) {
            my_s = csr_src[c0 + lane];
            float4 eav = ((const float4*)csr_ea)[c0 + lane];
            if (H == 4) {
                float4 as4 = *(const float4*)&a_s[(size_t)my_s * 4];
                float l0 = leaky02(as4.x + add_[0] + eav.x * vt[0][0] + eav.y * vt[1][0] + eav.z * vt[2][0] + eav.w * vt[3][0]);
                float l1 = leaky02(as4.y + add_[1] + eav.x * vt[0][1] + eav.y * vt[1][1] + eav.z * vt[2][1] + eav.w * vt[3][1]);
                float l2 = leaky02(as4.z + add_[2] + eav.x * vt[0][2] + eav.y * vt[1][2] + eav.z * vt[2][2] + eav.w * vt[3][2]);
                float l3 = leaky02(as4.w + add_[3] + eav.x * vt[0][3] + eav.y * vt[1][3] + eav.z * vt[2][3] + eav.w * vt[3][3]);
                w0 = __expf(l0 - lself[0]);
                w1 = __expf(l1 - lself[1]);
                w2 = __expf(l2 - lself[2]);
                w3 = __expf(l3 - lself[3]);
            } else {
                float l0 = leaky02(a_s[my_s] + add_[0] + eav.x * vt[0][0] + eav.y * vt[1][0] + eav.z * vt[2][0] + eav.w * vt[3][0]);
                w0 = __expf(l0 - lself[0]);
            }
        }
        int t = 0;
        for (; t + 8 <= nc; t += 8) {
            EDGE_STEP(t)
            EDGE_STEP(t + 1)
            EDGE_STEP(t + 2)
            EDGE_STEP(t + 3)
            EDGE_STEP(t + 4)
            EDGE_STEP(t + 5)
            EDGE_STEP(t + 6)
            EDGE_STEP(t + 7)
        }
        for (; t < nc; ++t) {
            EDGE_STEP(t)
        }
    }
#undef EDGE_STEP

    const float invz = 1.f / (zacc + 1e-16f);
    #pragma unroll
    for (int c = 0; c < CPT; ++c) {
        float v = acc[c] * invz + bias[colbase + c];
        if (ELU) v = (v > 0.f) ? v : (__expf(v) - 1.f);
        acc[c] = v;
    }
    if (CPT == 4) {
        __half2* op = (__half2*)(out + (size_t)d * HC + colbase);
        op[0] = __floats2half2_rn(acc[0], acc[1]);
        op[1] = __floats2half2_rn(acc[2], acc[3]);
    } else {
        out[(size_t)d * HC + colbase] = __float2half(acc[0]);
    }
}

// ---------------- global mean pool (hierarchical, fp16 in) ----------------
__global__ void pool_kernel(const __half* __restrict__ h3, const int* __restrict__ batch,
                            float* __restrict__ psum, float* __restrict__ pcnt) {
    __shared__ float s_acc[8][64];
    __shared__ float s_cnt[8];
    const int tid = threadIdx.x; // 256
    for (int i = tid; i < 512; i += 256) s_acc[i >> 6][i & 63] = 0.f;
    if (tid < 8) s_cnt[tid] = 0.f;
    __syncthreads();
    const int col = tid & 63, nl = tid >> 6;
    const int n0 = blockIdx.x * 64;
    for (int nn = nl; nn < 64; nn += 4) {
        int n = n0 + nn;
        if (n < N_NODES) {
            int b = batch[n];
            atomicAdd(&s_acc[b][col], __half2float(h3[(size_t)n * 64 + col]));
            if (col == 0) atomicAdd(&s_cnt[b], 1.0f);
        }
    }
    __syncthreads();
    for (int i = tid; i < 512; i += 256) {
        float v = s_acc[i >> 6][i & 63];
        if (v != 0.f) atomicAdd(&psum[i], v);
    }
    if (tid < 8 && s_cnt[tid] > 0.f) atomicAdd(&pcnt[tid], s_cnt[tid]);
}

// ---------------- head part 1: static_features ----------------
__global__ void head_sf_kernel(const float* __restrict__ psum, const float* __restrict__ pcnt,
                               const float* __restrict__ w1, const float* __restrict__ b1,
                               const float* __restrict__ w2, const float* __restrict__ b2,
                               float* __restrict__ out) {
    const int b = blockIdx.y;
    const int c0 = blockIdx.x * 128;
    const int tid = threadIdx.x; // 128
    __shared__ float s_g[64];
    __shared__ float s_p1[128];
    if (tid < 64) {
        float c = pcnt[b];
        c = (c < 1.f) ? 1.f : c;
        s_g[tid] = psum[b * 64 + tid] / c;
    }
    __syncthreads();
    {
        float a = b1[tid];
        #pragma unroll 8
        for (int k = 0; k < 64; ++k) a += s_g[k] * w1[k * 128 + tid];
        s_p1[tid] = fmaxf(a, 0.f);
    }
    __syncthreads();
    const int col = c0 + tid;
    float a = b2[col];
    #pragma unroll 8
    for (int k = 0; k < 128; ++k) a += s_p1[k] * w2[k * 768 + col];
    out[b * 768 + col] = a;
}

// ---------------- head part 2: vulnerability scores ----------------
__global__ void scores_kernel(const float* __restrict__ sf,
                              const float* __restrict__ vw, const float* __restrict__ vb,
                              float* __restrict__ out) {
    const int b = blockIdx.x;
    const int tid = threadIdx.x; // 256
    const int wave = tid >> 6, lane = tid & 63;
    float part[5] = {0.f, 0.f, 0.f, 0.f, 0.f};
    for (int k = tid; k < 768; k += 256) {
        float s = sf[b * 768 + k];
        #pragma unroll
        for (int v = 0; v < 5; ++v) part[v] += s * vw[k * 5 + v];
    }
    #pragma unroll
    for (int v = 0; v < 5; ++v)
        #pragma unroll
        for (int off = 32; off; off >>= 1) part[v] += __shfl_down(part[v], off, 64);
    __shared__ float sred[4][5];
    if (lane == 0) {
        #pragma unroll
        for (int v = 0; v < 5; ++v) sred[wave][v] = part[v];
    }
    __syncthreads();
    if (tid < 5) {
        float a = vb[tid] + sred[0][tid] + sred[1][tid] + sred[2][tid] + sred[3][tid];
        out[6144 + b * 5 + tid] = 1.f / (1.f + __expf(-a));
    }
}

extern "C" void kernel_launch(void* const* d_in, const int* in_sizes, int n_in,
                              void* d_out, int out_size, void* d_ws, size_t ws_size,
                              hipStream_t stream) {
    const float* x       = (const float*)d_in[0];
    const int*   eidx    = (const int*)d_in[1];
    const float* ea      = (const float*)d_in[2];
    const int*   batch   = (const int*)d_in[3];
    const float* enc_w1  = (const float*)d_in[4];
    const float* enc_b1  = (const float*)d_in[5];
    const float* enc_w2  = (const float*)d_in[6];
    const float* enc_b2  = (const float*)d_in[7];
    const float* g1_w    = (const float*)d_in[8];
    const float* g1_asrc = (const float*)d_in[9];
    const float* g1_adst = (const float*)d_in[10];
    const float* g1_we   = (const float*)d_in[11];
    const float* g1_ae   = (const float*)d_in[12];
    const float* g1_b    = (const float*)d_in[13];
    const float* g2_w    = (const float*)d_in[14];
    const float* g2_asrc = (const float*)d_in[15];
    const float* g2_adst = (const float*)d_in[16];
    const float* g2_we   = (const float*)d_in[17];
    const float* g2_ae   = (const float*)d_in[18];
    const float* g2_b    = (const float*)d_in[19];
    const float* g3_w    = (const float*)d_in[20];
    const float* g3_asrc = (const float*)d_in[21];
    const float* g3_adst = (const float*)d_in[22];
    const float* g3_we   = (const float*)d_in[23];
    const float* g3_ae   = (const float*)d_in[24];
    const float* g3_b    = (const float*)d_in[25];
    const float* pw1     = (const float*)d_in[26];
    const float* pb1     = (const float*)d_in[27];
    const float* pw2     = (const float*)d_in[28];
    const float* pb2     = (const float*)d_in[29];
    const float* vw      = (const float*)d_in[30];
    const float* vb      = (const float*)d_in[31];

    const int* src = eidx;
    const int* dst = eidx + N_EDGES;

    // ---- workspace layout ----
    __half* h16a = (__half*)d_ws;                           // [M_PAD][256] f16
    __half* h16b = h16a + (size_t)M_PAD * 256;              // [M_PAD][256] f16
    __half* hh16 = h16b + (size_t)M_PAD * 256;              // [M_PAD][256] f16
    __half* wt1  = hh16 + (size_t)M_PAD * 256;              // [256][128]
    __half* wt2  = wt1 + 32768;                             // [256][256]
    __half* wt3  = wt2 + 65536;                             // [64][256]
    float* asb   = (float*)(wt3 + 16384);                   // [M_PAD][4]
    float* adb   = asb + (size_t)M_PAD * 4;                 // [M_PAD][4]
    float* zreg  = adb + (size_t)M_PAD * 4;
    float* ea_sum = zreg;                                   // 4
    float* psum   = zreg + 4;                               // 512
    float* pcnt   = zreg + 516;                             // 8
    float* vtab   = zreg + 524;                             // 3*16
    float* lpae   = zreg + 572;                             // 3*4
    int* icnt    = (int*)(zreg + 584);                      // N
    int* icur    = icnt + N_NODES;                          // N
    int* irow    = icur + N_NODES;                          // N+16
    int* csr_src = irow + N_NODES + 16;                     // E
    float* csr_ea = (float*)(csr_src + N_EDGES);            // E*4 (16B aligned)

    hipMemsetAsync(zreg, 0, 584 * sizeof(float), stream);
    hipMemsetAsync(icnt, 0, 2 * N_NODES * sizeof(int), stream);

    prep_kernel<<<256, 256, 0, stream>>>(ea, dst, ea_sum, icnt);
    encoder_kernel<<<N_NODES / 8, 128, 0, stream>>>(x, enc_w1, enc_b1, enc_w2, enc_b2, h16a);
    scan_kernel<<<1, 1024, 0, stream>>>(icnt, irow);
    scatter_kernel<<<(N_EDGES + 255) / 256, 256, 0, stream>>>(src, dst, ea, irow, icur, csr_src, csr_ea);
    const_prep_kernel<<<451, 256, 0, stream>>>(g1_w, g2_w, g3_w, wt1, wt2, wt3,
                                               g1_we, g1_ae, g2_we, g2_ae, g3_we, g3_ae,
                                               ea_sum, vtab, lpae);

    // layer 1: K=128 -> HC=256, H=4, ELU      (h16a -> hh16 -> h16b)
    mgemm_kernel<256, 4><<<dim3(M_PAD / 64, 4), 256, 0, stream>>>(h16a, wt1, g1_asrc, g1_adst, hh16, asb, adb, 128);
    agg4_kernel<4, 256, true><<<N_NODES / 4, 256, 0, stream>>>(hh16, asb, adb, vtab, lpae, csr_src, csr_ea, irow, g1_b, h16b);

    // layer 2: K=256 -> HC=256, H=4, ELU      (h16b -> hh16 -> h16a)
    mgemm_kernel<256, 4><<<dim3(M_PAD / 64, 4), 256, 0, stream>>>(h16b, wt2, g2_asrc, g2_adst, hh16, asb, adb, 256);
    agg4_kernel<4, 256, true><<<N_NODES / 4, 256, 0, stream>>>(hh16, asb, adb, vtab + 16, lpae + 4, csr_src, csr_ea, irow, g2_b, h16a);

    // layer 3: K=256 -> HC=64, H=1, no ELU    (h16a -> hh16 -> h16b)
    mgemm_kernel<64, 1><<<dim3(M_PAD / 64, 1), 256, 0, stream>>>(h16a, wt3, g3_asrc, g3_adst, hh16, asb, adb, 256);
    agg4_kernel<1, 64, false><<<N_NODES / 4, 256, 0, stream>>>(hh16, asb, adb, vtab + 32, lpae + 8, csr_src, csr_ea, irow, g3_b, h16b);

    pool_kernel<<<(N_NODES + 63) / 64, 256, 0, stream>>>(h16b, batch, psum, pcnt);
    head_sf_kernel<<<dim3(6, 8), 128, 0, stream>>>(psum, pcnt, pw1, pb1, pw2, pb2, (float*)d_out);
    scores_kernel<<<8, 256, 0, stream>>>((float*)d_out, vw, vb, (float*)d_out);
}

// Round 8
// 315.075 us; speedup vs baseline: 3.2332x; 1.0211x over previous
//
#include <hip/hip_runtime.h>
#include <hip/hip_bf16.h>
#include <hip/hip_fp16.h>
#include <math.h>

#define N_NODES 20000
#define M_PAD 20096   // 314 * 64
#define N_EDGES 320000
#define N_GRAPHS 8

typedef _Float16 half8 __attribute__((ext_vector_type(8)));
typedef float floatx4 __attribute__((ext_vector_type(4)));

struct h4pack { __half2 a, b; }; // 8B, 4x fp16

__device__ __forceinline__ float leaky02(float x) { return x > 0.f ? x : 0.2f * x; }

// ---------------- encoder: x[N,5] -> relu -> [N,64] -> relu -> [N,128] (fp16 out) --------
__global__ void encoder_kernel(const float* __restrict__ x,
                               const float* __restrict__ w1, const float* __restrict__ b1,
                               const float* __restrict__ w2, const float* __restrict__ b2,
                               __half* __restrict__ out) {
    const int n0 = blockIdx.x * 8;
    const int tid = threadIdx.x; // 128
    __shared__ float s_x[8][5];
    __shared__ float s_h1[8][64];
    if (tid < 40) s_x[tid / 5][tid % 5] = x[(size_t)(n0 + tid / 5) * 5 + (tid % 5)];
    __syncthreads();
    if (tid < 64) {
        #pragma unroll
        for (int n = 0; n < 8; ++n) {
            float a = b1[tid];
            #pragma unroll
            for (int k = 0; k < 5; ++k) a += s_x[n][k] * w1[k * 64 + tid];
            s_h1[n][tid] = fmaxf(a, 0.f);
        }
    }
    __syncthreads();
    float acc[8];
    #pragma unroll
    for (int n = 0; n < 8; ++n) acc[n] = b2[tid];
    for (int k = 0; k < 64; ++k) {
        float wv = w2[k * 128 + tid];
        #pragma unroll
        for (int n = 0; n < 8; ++n) acc[n] += s_h1[n][k] * wv;
    }
    #pragma unroll
    for (int n = 0; n < 8; ++n)
        out[(size_t)(n0 + n) * 128 + tid] = __float2half(fmaxf(acc[n], 0.f));
}

// ---------------- prep: edge_attr sum + per-dst degree count (fused) ----------------
__global__ void prep_kernel(const float* __restrict__ ea, const int* __restrict__ dst,
                            float* __restrict__ ea_sum, int* __restrict__ cnt) {
    const int tid = threadIdx.x;
    float a0 = 0, a1 = 0, a2 = 0, a3 = 0;
    for (int i = blockIdx.x * blockDim.x + tid; i < N_EDGES; i += gridDim.x * blockDim.x) {
        float4 v = ((const float4*)ea)[i];
        a0 += v.x; a1 += v.y; a2 += v.z; a3 += v.w;
        atomicAdd(&cnt[dst[i]], 1);
    }
    #pragma unroll
    for (int off = 32; off; off >>= 1) {
        a0 += __shfl_down(a0, off, 64);
        a1 += __shfl_down(a1, off, 64);
        a2 += __shfl_down(a2, off, 64);
        a3 += __shfl_down(a3, off, 64);
    }
    __shared__ float s[4][4];
    const int wave = tid >> 6, lane = tid & 63;
    if (lane == 0) { s[wave][0] = a0; s[wave][1] = a1; s[wave][2] = a2; s[wave][3] = a3; }
    __syncthreads();
    if (tid < 4) {
        float t = s[0][tid] + s[1][tid] + s[2][tid] + s[3][tid];
        atomicAdd(&ea_sum[tid], t);
    }
}

__global__ void scan_kernel(const int* __restrict__ cnt, int* __restrict__ row_ptr) {
    __shared__ int s_sum[1024];
    const int tid = threadIdx.x;
    int local[20];
    int run = 0;
    const int base = tid * 20;
    #pragma unroll
    for (int i = 0; i < 20; ++i) {
        int idx = base + i;
        int v = (idx < N_NODES) ? cnt[idx] : 0;
        run += v;
        local[i] = run;
    }
    s_sum[tid] = run;
    __syncthreads();
    for (int off = 1; off < 1024; off <<= 1) {
        int v = (tid >= off) ? s_sum[tid - off] : 0;
        __syncthreads();
        s_sum[tid] += v;
        __syncthreads();
    }
    const int prev = (tid > 0) ? s_sum[tid - 1] : 0;
    #pragma unroll
    for (int i = 0; i < 20; ++i) {
        int idx = base + i;
        if (idx < N_NODES) row_ptr[idx + 1] = prev + local[i];
    }
    if (tid == 0) row_ptr[0] = 0;
}

// direct scatter: one packed 16B record {src, 4x fp16 ea} per edge
__global__ void scatter_kernel(const int* __restrict__ src, const int* __restrict__ dst,
                               const float* __restrict__ ea,
                               const int* __restrict__ row_ptr, int* __restrict__ cur,
                               int4* __restrict__ csr_edges) {
    int i = blockIdx.x * 256 + threadIdx.x;
    if (i < N_EDGES) {
        int d = dst[i];
        int p = atomicAdd(&cur[d], 1);
        int idx = row_ptr[d] + p;
        float4 e = ((const float4*)ea)[i];
        __half2 h01 = __floats2half2_rn(e.x, e.y);
        __half2 h23 = __floats2half2_rn(e.z, e.w);
        int4 r;
        r.x = src[i];
        r.y = *(int*)&h01;
        r.z = *(int*)&h23;
        r.w = 0;
        csr_edges[idx] = r;
    }
}

// ---------------- const prep: weight transpose/convert (blocks 0-447) + vtab (448-450) ----
__global__ void const_prep_kernel(const float* __restrict__ w1, const float* __restrict__ w2,
                                  const float* __restrict__ w3,
                                  __half* __restrict__ wt1, __half* __restrict__ wt2,
                                  __half* __restrict__ wt3,
                                  const float* __restrict__ we1, const float* __restrict__ ae1,
                                  const float* __restrict__ we2, const float* __restrict__ ae2,
                                  const float* __restrict__ we3, const float* __restrict__ ae3,
                                  const float* __restrict__ ea_sum,
                                  float* __restrict__ vtab, float* __restrict__ lpae) {
    const int b = blockIdx.x;
    if (b < 448) {
        int i = b * 256 + threadIdx.x;
        if (i < 32768) {                       // g1: K=128, N=256
            int k = i >> 8, n = i & 255;
            wt1[(size_t)n * 128 + k] = __float2half(w1[i]);
        } else if (i < 98304) {                // g2: K=256, N=256
            int j = i - 32768;
            int k = j >> 8, n = j & 255;
            wt2[(size_t)n * 256 + k] = __float2half(w2[j]);
        } else if (i < 114688) {               // g3: K=256, N=64
            int j = i - 98304;
            int k = j >> 6, n = j & 63;
            wt3[(size_t)n * 256 + k] = __float2half(w3[j]);
        }
        return;
    }
    const int L = b - 448;
    const float* We = (L == 0) ? we1 : ((L == 1) ? we2 : we3);
    const float* Ae = (L == 0) ? ae1 : ((L == 1) ? ae2 : ae3);
    const int H = (L < 2) ? 4 : 1;
    const int tid = threadIdx.x;
    __shared__ float s_v[16];
    if (tid < 4 * H) {
        const int k = tid / H, h = tid % H;
        float v = 0.f;
        for (int c = 0; c < 64; ++c) v += We[k * (H * 64) + h * 64 + c] * Ae[h * 64 + c];
        vtab[L * 16 + k * 4 + h] = v;
        s_v[k * 4 + h] = v;
    }
    __syncthreads();
    if (tid < H) {
        const float inv = 1.0f / (float)N_EDGES;
        float l = 0.f;
        #pragma unroll
        for (int k = 0; k < 4; ++k) l += ea_sum[k] * inv * s_v[k * 4 + tid];
        lpae[L * 4 + tid] = l;
    }
}

// ---------------- MFMA GEMM + fused attention scalars (K-step 64) ----------------
template<int N, int H>
__global__ __launch_bounds__(256) void mgemm_kernel(
    const __half* __restrict__ X, const __half* __restrict__ Wt,
    const float* __restrict__ asrc, const float* __restrict__ adst,
    __half* __restrict__ Y, float* __restrict__ a_s, float* __restrict__ a_d, int K) {
    constexpr int STR = 72;
    __shared__ _Float16 sX[64 * STR];
    __shared__ _Float16 sW[64 * STR];
    const int tid = threadIdx.x;
    const int lane = tid & 63, w = tid >> 6;
    const int l16 = lane & 15, kg = lane >> 4;
    const int n0 = blockIdx.x * 64;
    const int c0 = blockIdx.y * 64;
    const int by = blockIdx.y;

    floatx4 acc[4];
    #pragma unroll
    for (int ct = 0; ct < 4; ++ct) acc[ct] = (floatx4){0.f, 0.f, 0.f, 0.f};

    const int srow = tid >> 2, sseg = tid & 3;
    for (int k0 = 0; k0 < K; k0 += 64) {
        float4 xv0 = *(const float4*)(X + (size_t)(n0 + srow) * K + k0 + sseg * 8);
        float4 xv1 = *(const float4*)(X + (size_t)(n0 + srow) * K + k0 + 32 + sseg * 8);
        float4 wv0 = *(const float4*)(Wt + (size_t)(c0 + srow) * K + k0 + sseg * 8);
        float4 wv1 = *(const float4*)(Wt + (size_t)(c0 + srow) * K + k0 + 32 + sseg * 8);
        __syncthreads();
        *(float4*)&sX[srow * STR + sseg * 8] = xv0;
        *(float4*)&sX[srow * STR + 32 + sseg * 8] = xv1;
        *(float4*)&sW[srow * STR + sseg * 8] = wv0;
        *(float4*)&sW[srow * STR + 32 + sseg * 8] = wv1;
        __syncthreads();
        #pragma unroll
        for (int ks = 0; ks < 2; ++ks) {
            half8 a = *(const half8*)&sX[(w * 16 + l16) * STR + ks * 32 + kg * 8];
            #pragma unroll
            for (int ct = 0; ct < 4; ++ct) {
                half8 b = *(const half8*)&sW[(ct * 16 + l16) * STR + ks * 32 + kg * 8];
                acc[ct] = __builtin_amdgcn_mfma_f32_16x16x32_f16(a, b, acc[ct], 0, 0, 0);
            }
        }
    }

    // epilogue: C/D layout col = lane&15, row = (lane>>4)*4 + reg
    const int rowb = n0 + w * 16 + kg * 4;
    float ar[4], ad4[4];
    #pragma unroll
    for (int ct = 0; ct < 4; ++ct) {
        ar[ct] = asrc[c0 + ct * 16 + l16];
        ad4[ct] = adst[c0 + ct * 16 + l16];
    }
    #pragma unroll
    for (int ct = 0; ct < 4; ++ct) {
        const int col = c0 + ct * 16 + l16;
        #pragma unroll
        for (int r = 0; r < 4; ++r)
            Y[(size_t)(rowb + r) * N + col] = __float2half(acc[ct][r]);
    }
    #pragma unroll
    for (int r = 0; r < 4; ++r) {
        float p = acc[0][r] * ar[0] + acc[1][r] * ar[1] + acc[2][r] * ar[2] + acc[3][r] * ar[3];
        float q = acc[0][r] * ad4[0] + acc[1][r] * ad4[1] + acc[2][r] * ad4[2] + acc[3][r] * ad4[3];
        #pragma unroll
        for (int off = 1; off < 16; off <<= 1) {
            p += __shfl_xor(p, off, 64);
            q += __shfl_xor(q, off, 64);
        }
        if (l16 == 0) {
            const int node = rowb + r;
            a_s[(size_t)node * H + by] = p;
            a_d[(size_t)node * H + by] = q;
        }
    }
}

// ---------------- GAT aggregation: wave per node, self-shift softmax, packed edges ----------
// H=4: producer lane packs w0..w3 into two half2 words -> 3 shfls/step instead of 5.
template<int H, int HC, bool ELU>
__global__ __launch_bounds__(256) void agg5_kernel(
    const __half* __restrict__ hh,
    const float* __restrict__ a_s, const float* __restrict__ a_d,
    const float* __restrict__ vtab, const float* __restrict__ lpae,
    const int4* __restrict__ csr_edges,
    const int* __restrict__ row_ptr, const float* __restrict__ bias,
    __half* __restrict__ out) {
    constexpr int CPT = HC / 64;
    const int wave = threadIdx.x >> 6;
    const int lane = threadIdx.x & 63;
    const int d = blockIdx.x * 4 + wave;

    const int base = row_ptr[d], end = row_ptr[d + 1];
    const int colbase = lane * CPT;
    const int hl = (H == 1) ? 0 : (colbase >> 6);

    float vt[4][H];
    #pragma unroll
    for (int k = 0; k < 4; ++k)
        #pragma unroll
        for (int h = 0; h < H; ++h) vt[k][h] = vtab[k * 4 + h];

    float add_[H], lself[H];
    if (H == 4) {
        float4 t = *(const float4*)&a_d[(size_t)d * 4];
        add_[0] = t.x; add_[1] = t.y; add_[2] = t.z; add_[3] = t.w;
        float4 s4 = *(const float4*)&a_s[(size_t)d * 4];
        lself[0] = leaky02(s4.x + add_[0] + lpae[0]);
        lself[1] = leaky02(s4.y + add_[1] + lpae[1]);
        lself[2] = leaky02(s4.z + add_[2] + lpae[2]);
        lself[3] = leaky02(s4.w + add_[3] + lpae[3]);
    } else {
        add_[0] = a_d[d];
        lself[0] = leaky02(a_s[d] + add_[0] + lpae[0]);
    }

    // self-loop term: w_self = exp(lself - lself) = 1
    float zacc = 1.f;
    float acc[CPT];
    if (CPT == 4) {
        h4pack hv = *(const h4pack*)(hh + (size_t)d * HC + colbase);
        float2 f0 = __half22float2(hv.a);
        float2 f1 = __half22float2(hv.b);
        acc[0] = f0.x; acc[1] = f0.y; acc[2] = f1.x; acc[3] = f1.y;
    } else {
        acc[0] = __half2float(hh[(size_t)d * HC + colbase]);
    }

#define EDGE_STEP(tt) { \
        int s_ = __shfl(my_s, (tt), 64); \
        float w_; \
        if (H == 4) { \
            int t01 = __shfl(wp01, (tt), 64); \
            int t23 = __shfl(wp23, (tt), 64); \
            int selw = (hl < 2) ? t01 : t23; \
            __half2 hpw = *(__half2*)&selw; \
            float2 fw = __half22float2(hpw); \
            w_ = (hl & 1) ? fw.y : fw.x; \
        } else { \
            w_ = __shfl(w0, (tt), 64); \
        } \
        if (CPT == 4) { \
            h4pack hv_ = *(const h4pack*)(hh + (size_t)s_ * HC + colbase); \
            float2 f0_ = __half22float2(hv_.a); \
            float2 f1_ = __half22float2(hv_.b); \
            acc[0] += w_ * f0_.x; acc[1] += w_ * f0_.y; \
            acc[2] += w_ * f1_.x; acc[3] += w_ * f1_.y; \
        } else { \
            acc[0] += w_ * __half2float(hh[(size_t)s_ * HC + colbase]); \
        } \
        zacc += w_; }

    for (int c0 = base; c0 < end; c0 += 64) {
        const int nc = min(64, end - c0);
        int my_s = 0;
        int wp01 = 0, wp23 = 0;
        float w0 = 0.f;
        if (lane < nc) {
            int4 er = csr_edges[c0 + lane];
            my_s = er.x;
            __half2 h01 = *(__half2*)&er.y;
            __half2 h23 = *(__half2*)&er.z;
            float2 e01 = __half22float2(h01);
            float2 e23 = __half22float2(h23);
            if (H == 4) {
                float4 as4 = *(const float4*)&a_s[(size_t)my_s * 4];
                float l0 = leaky02(as4.x + add_[0] + e01.x * vt[0][0] + e01.y * vt[1][0] + e23.x * vt[2][0] + e23.y * vt[3][0]);
                float l1 = leaky02(as4.y + add_[1] + e01.x * vt[0][1] + e01.y * vt[1][1] + e23.x * vt[2][1] + e23.y * vt[3][1]);
                float l2 = leaky02(as4.z + add_[2] + e01.x * vt[0][2] + e01.y * vt[1][2] + e23.x * vt[2][2] + e23.y * vt[3][2]);
                float l3 = leaky02(as4.w + add_[3] + e01.x * vt[0][3] + e01.y * vt[1][3] + e23.x * vt[2][3] + e23.y * vt[3][3]);
                __half2 p01 = __floats2half2_rn(__expf(l0 - lself[0]), __expf(l1 - lself[1]));
                __half2 p23 = __floats2half2_rn(__expf(l2 - lself[2]), __expf(l3 - lself[3]));
                wp01 = *(int*)&p01;
                wp23 = *(int*)&p23;
            } else {
                float l0 = leaky02(a_s[my_s] + add_[0] + e01.x * vt[0][0] + e01.y * vt[1][0] + e23.x * vt[2][0] + e23.y * vt[3][0]);
                w0 = __expf(l0 - lself[0]);
            }
        }
        int t = 0;
        for (; t + 8 <= nc; t += 8) {
            EDGE_STEP(t)
            EDGE_STEP(t + 1)
            EDGE_STEP(t + 2)
            EDGE_STEP(t + 3)
            EDGE_STEP(t + 4)
            EDGE_STEP(t + 5)
            EDGE_STEP(t + 6)
            EDGE_STEP(t + 7)
        }
        for (; t < nc; ++t) {
            EDGE_STEP(t)
        }
    }
#undef EDGE_STEP

    const float invz = 1.f / (zacc + 1e-16f);
    #pragma unroll
    for (int c = 0; c < CPT; ++c) {
        float v = acc[c] * invz + bias[colbase + c];
        if (ELU) v = (v > 0.f) ? v : (__expf(v) - 1.f);
        acc[c] = v;
    }
    if (CPT == 4) {
        __half2* op = (__half2*)(out + (size_t)d * HC + colbase);
        op[0] = __floats2half2_rn(acc[0], acc[1]);
        op[1] = __floats2half2_rn(acc[2], acc[3]);
    } else {
        out[(size_t)d * HC + colbase] = __float2half(acc[0]);
    }
}

// ---------------- global mean pool (hierarchical, fp16 in) ----------------
__global__ void pool_kernel(const __half* __restrict__ h3, const int* __restrict__ batch,
                            float* __restrict__ psum, float* __restrict__ pcnt) {
    __shared__ float s_acc[8][64];
    __shared__ float s_cnt[8];
    const int tid = threadIdx.x; // 256
    for (int i = tid; i < 512; i += 256) s_acc[i >> 6][i & 63] = 0.f;
    if (tid < 8) s_cnt[tid] = 0.f;
    __syncthreads();
    const int col = tid & 63, nl = tid >> 6;
    const int n0 = blockIdx.x * 64;
    for (int nn = nl; nn < 64; nn += 4) {
        int n = n0 + nn;
        if (n < N_NODES) {
            int b = batch[n];
            atomicAdd(&s_acc[b][col], __half2float(h3[(size_t)n * 64 + col]));
            if (col == 0) atomicAdd(&s_cnt[b], 1.0f);
        }
    }
    __syncthreads();
    for (int i = tid; i < 512; i += 256) {
        float v = s_acc[i >> 6][i & 63];
        if (v != 0.f) atomicAdd(&psum[i], v);
    }
    if (tid < 8 && s_cnt[tid] > 0.f) atomicAdd(&pcnt[tid], s_cnt[tid]);
}

// ---------------- fused head: g -> p1 -> static_features -> scores (block = graph) --------
__global__ void head_kernel(const float* __restrict__ psum, const float* __restrict__ pcnt,
                            const float* __restrict__ w1, const float* __restrict__ b1,
                            const float* __restrict__ w2, const float* __restrict__ b2,
                            const float* __restrict__ vw, const float* __restrict__ vb,
                            float* __restrict__ out) {
    const int b = blockIdx.x;
    const int tid = threadIdx.x; // 768
    const int wave = tid >> 6, lane = tid & 63;
    __shared__ float s_g[64];
    __shared__ float s_p1[128];
    __shared__ float s_red[12][5];
    if (tid < 64) {
        float c = pcnt[b];
        c = (c < 1.f) ? 1.f : c;
        s_g[tid] = psum[b * 64 + tid] / c;
    }
    __syncthreads();
    if (tid < 128) {
        float a = b1[tid];
        #pragma unroll 8
        for (int k = 0; k < 64; ++k) a += s_g[k] * w1[k * 128 + tid];
        s_p1[tid] = fmaxf(a, 0.f);
    }
    __syncthreads();
    float a = b2[tid];
    #pragma unroll 8
    for (int k = 0; k < 128; ++k) a += s_p1[k] * w2[k * 768 + tid];
    out[b * 768 + tid] = a;

    float part[5];
    #pragma unroll
    for (int v = 0; v < 5; ++v) part[v] = a * vw[tid * 5 + v];
    #pragma unroll
    for (int v = 0; v < 5; ++v)
        #pragma unroll
        for (int off = 32; off; off >>= 1) part[v] += __shfl_down(part[v], off, 64);
    if (lane == 0) {
        #pragma unroll
        for (int v = 0; v < 5; ++v) s_red[wave][v] = part[v];
    }
    __syncthreads();
    if (tid < 5) {
        float acc = vb[tid];
        #pragma unroll
        for (int w = 0; w < 12; ++w) acc += s_red[w][tid];
        out[6144 + b * 5 + tid] = 1.f / (1.f + __expf(-acc));
    }
}

extern "C" void kernel_launch(void* const* d_in, const int* in_sizes, int n_in,
                              void* d_out, int out_size, void* d_ws, size_t ws_size,
                              hipStream_t stream) {
    const float* x       = (const float*)d_in[0];
    const int*   eidx    = (const int*)d_in[1];
    const float* ea      = (const float*)d_in[2];
    const int*   batch   = (const int*)d_in[3];
    const float* enc_w1  = (const float*)d_in[4];
    const float* enc_b1  = (const float*)d_in[5];
    const float* enc_w2  = (const float*)d_in[6];
    const float* enc_b2  = (const float*)d_in[7];
    const float* g1_w    = (const float*)d_in[8];
    const float* g1_asrc = (const float*)d_in[9];
    const float* g1_adst = (const float*)d_in[10];
    const float* g1_we   = (const float*)d_in[11];
    const float* g1_ae   = (const float*)d_in[12];
    const float* g1_b    = (const float*)d_in[13];
    const float* g2_w    = (const float*)d_in[14];
    const float* g2_asrc = (const float*)d_in[15];
    const float* g2_adst = (const float*)d_in[16];
    const float* g2_we   = (const float*)d_in[17];
    const float* g2_ae   = (const float*)d_in[18];
    const float* g2_b    = (const float*)d_in[19];
    const float* g3_w    = (const float*)d_in[20];
    const float* g3_asrc = (const float*)d_in[21];
    const float* g3_adst = (const float*)d_in[22];
    const float* g3_we   = (const float*)d_in[23];
    const float* g3_ae   = (const float*)d_in[24];
    const float* g3_b    = (const float*)d_in[25];
    const float* pw1     = (const float*)d_in[26];
    const float* pb1     = (const float*)d_in[27];
    const float* pw2     = (const float*)d_in[28];
    const float* pb2     = (const float*)d_in[29];
    const float* vw      = (const float*)d_in[30];
    const float* vb      = (const float*)d_in[31];

    const int* src = eidx;
    const int* dst = eidx + N_EDGES;

    // ---- workspace layout ----
    __half* h16a = (__half*)d_ws;                           // [M_PAD][256] f16
    __half* h16b = h16a + (size_t)M_PAD * 256;              // [M_PAD][256] f16
    __half* hh16 = h16b + (size_t)M_PAD * 256;              // [M_PAD][256] f16
    __half* wt1  = hh16 + (size_t)M_PAD * 256;              // [256][128]
    __half* wt2  = wt1 + 32768;                             // [256][256]
    __half* wt3  = wt2 + 65536;                             // [64][256]
    float* asb   = (float*)(wt3 + 16384);                   // [M_PAD][4]
    float* adb   = asb + (size_t)M_PAD * 4;                 // [M_PAD][4]
    float* zreg  = adb + (size_t)M_PAD * 4;
    float* ea_sum = zreg;                                   // 4
    float* psum   = zreg + 4;                               // 512
    float* pcnt   = zreg + 516;                             // 8
    float* vtab   = zreg + 524;                             // 3*16
    float* lpae   = zreg + 572;                             // 3*4
    int* icnt    = (int*)(zreg + 584);                      // N
    int* icur    = icnt + N_NODES;                          // N
    int* irow    = icur + N_NODES;                          // N+16
    int4* csr_edges = (int4*)(irow + N_NODES + 16);         // E x 16B (16B aligned)

    hipMemsetAsync(zreg, 0, 584 * sizeof(float), stream);
    hipMemsetAsync(icnt, 0, 2 * N_NODES * sizeof(int), stream);

    prep_kernel<<<256, 256, 0, stream>>>(ea, dst, ea_sum, icnt);
    encoder_kernel<<<N_NODES / 8, 128, 0, stream>>>(x, enc_w1, enc_b1, enc_w2, enc_b2, h16a);
    scan_kernel<<<1, 1024, 0, stream>>>(icnt, irow);
    scatter_kernel<<<(N_EDGES + 255) / 256, 256, 0, stream>>>(src, dst, ea, irow, icur, csr_edges);
    const_prep_kernel<<<451, 256, 0, stream>>>(g1_w, g2_w, g3_w, wt1, wt2, wt3,
                                               g1_we, g1_ae, g2_we, g2_ae, g3_we, g3_ae,
                                               ea_sum, vtab, lpae);

    // layer 1: K=128 -> HC=256, H=4, ELU      (h16a -> hh16 -> h16b)
    mgemm_kernel<256, 4><<<dim3(M_PAD / 64, 4), 256, 0, stream>>>(h16a, wt1, g1_asrc, g1_adst, hh16, asb, adb, 128);
    agg5_kernel<4, 256, true><<<N_NODES / 4, 256, 0, stream>>>(hh16, asb, adb, vtab, lpae, csr_edges, irow, g1_b, h16b);

    // layer 2: K=256 -> HC=256, H=4, ELU      (h16b -> hh16 -> h16a)
    mgemm_kernel<256, 4><<<dim3(M_PAD / 64, 4), 256, 0, stream>>>(h16b, wt2, g2_asrc, g2_adst, hh16, asb, adb, 256);
    agg5_kernel<4, 256, true><<<N_NODES / 4, 256, 0, stream>>>(hh16, asb, adb, vtab + 16, lpae + 4, csr_edges, irow, g2_b, h16a);

    // layer 3: K=256 -> HC=64, H=1, no ELU    (h16a -> hh16 -> h16b)
    mgemm_kernel<64, 1><<<dim3(M_PAD / 64, 1), 256, 0, stream>>>(h16a, wt3, g3_asrc, g3_adst, hh16, asb, adb, 256);
    agg5_kernel<1, 64, false><<<N_NODES / 4, 256, 0, stream>>>(hh16, asb, adb, vtab + 32, lpae + 8, csr_edges, irow, g3_b, h16b);

    pool_kernel<<<(N_NODES + 63) / 64, 256, 0, stream>>>(h16b, batch, psum, pcnt);
    head_kernel<<<8, 768, 0, stream>>>(psum, pcnt, pw1, pb1, pw2, pb2, vw, vb, (float*)d_out);
}

// Round 9
// 302.039 us; speedup vs baseline: 3.3727x; 1.0432x over previous
//
#include <hip/hip_runtime.h>
#include <hip/hip_bf16.h>
#include <hip/hip_fp16.h>
#include <math.h>

#define N_NODES 20000
#define M_PAD 20096   // 314 * 64
#define N_EDGES 320000
#define N_GRAPHS 8

typedef _Float16 half8 __attribute__((ext_vector_type(8)));
typedef float floatx4 __attribute__((ext_vector_type(4)));

struct h4pack { __half2 a, b; }; // 8B, 4x fp16

__device__ __forceinline__ float leaky02(float x) { return x > 0.f ? x : 0.2f * x; }

// ---------------- fused prologue ----------------
// blocks 0-255   : prep (ea_sum + per-dst degree count)
// blocks 256-703 : weight transpose/convert fp32->fp16 (3 layers)
// blocks 704-1953: encoder, 16 nodes/block (x[N,5]->relu->64->relu->128, fp16 out)
__global__ __launch_bounds__(256) void fused_prep_kernel(
    const float* __restrict__ ea, const int* __restrict__ dst,
    float* __restrict__ ea_sum, int* __restrict__ cnt,
    const float* __restrict__ w1g, const float* __restrict__ w2g, const float* __restrict__ w3g,
    __half* __restrict__ wt1, __half* __restrict__ wt2, __half* __restrict__ wt3,
    const float* __restrict__ x,
    const float* __restrict__ ew1, const float* __restrict__ eb1,
    const float* __restrict__ ew2, const float* __restrict__ eb2,
    __half* __restrict__ enc_out) {
    const int b = blockIdx.x;
    const int tid = threadIdx.x;
    __shared__ float s_red[4][4];
    __shared__ float e_x[16][5];
    __shared__ float e_h1[16][64];

    if (b < 256) {
        // ---- prep ----
        float a0 = 0, a1 = 0, a2 = 0, a3 = 0;
        for (int i = b * 256 + tid; i < N_EDGES; i += 65536) {
            float4 v = ((const float4*)ea)[i];
            a0 += v.x; a1 += v.y; a2 += v.z; a3 += v.w;
            atomicAdd(&cnt[dst[i]], 1);
        }
        #pragma unroll
        for (int off = 32; off; off >>= 1) {
            a0 += __shfl_down(a0, off, 64);
            a1 += __shfl_down(a1, off, 64);
            a2 += __shfl_down(a2, off, 64);
            a3 += __shfl_down(a3, off, 64);
        }
        const int wave = tid >> 6, lane = tid & 63;
        if (lane == 0) { s_red[wave][0] = a0; s_red[wave][1] = a1; s_red[wave][2] = a2; s_red[wave][3] = a3; }
        __syncthreads();
        if (tid < 4) {
            float t = s_red[0][tid] + s_red[1][tid] + s_red[2][tid] + s_red[3][tid];
            atomicAdd(&ea_sum[tid], t);
        }
        return;
    }
    if (b < 704) {
        // ---- weight convert/transpose ----
        int i = (b - 256) * 256 + tid;
        if (i < 32768) {                       // g1: K=128, N=256
            int k = i >> 8, n = i & 255;
            wt1[(size_t)n * 128 + k] = __float2half(w1g[i]);
        } else if (i < 98304) {                // g2: K=256, N=256
            int j = i - 32768;
            int k = j >> 8, n = j & 255;
            wt2[(size_t)n * 256 + k] = __float2half(w2g[j]);
        } else if (i < 114688) {               // g3: K=256, N=64
            int j = i - 98304;
            int k = j >> 6, n = j & 63;
            wt3[(size_t)n * 256 + k] = __float2half(w3g[j]);
        }
        return;
    }
    // ---- encoder: 16 nodes per block ----
    const int n0 = (b - 704) * 16;
    const int sub = tid >> 7;   // 0/1: which 8-node half
    const int t7 = tid & 127;
    if (t7 < 40) e_x[sub * 8 + t7 / 5][t7 % 5] = x[(size_t)(n0 + sub * 8 + t7 / 5) * 5 + (t7 % 5)];
    __syncthreads();
    if (t7 < 64) {
        #pragma unroll
        for (int n = 0; n < 8; ++n) {
            float a = eb1[t7];
            #pragma unroll
            for (int k = 0; k < 5; ++k) a += e_x[sub * 8 + n][k] * ew1[k * 64 + t7];
            e_h1[sub * 8 + n][t7] = fmaxf(a, 0.f);
        }
    }
    __syncthreads();
    float acc[8];
    #pragma unroll
    for (int n = 0; n < 8; ++n) acc[n] = eb2[t7];
    for (int k = 0; k < 64; ++k) {
        float wv = ew2[k * 128 + t7];
        #pragma unroll
        for (int n = 0; n < 8; ++n) acc[n] += e_h1[sub * 8 + n][k] * wv;
    }
    #pragma unroll
    for (int n = 0; n < 8; ++n)
        enc_out[(size_t)(n0 + sub * 8 + n) * 128 + t7] = __float2half(fmaxf(acc[n], 0.f));
}

// ---------------- scan (1 block) + vtab/lpae for all 3 layers ----------------
__global__ void scan_kernel(const int* __restrict__ cnt, int* __restrict__ row_ptr,
                            const float* __restrict__ we1, const float* __restrict__ ae1,
                            const float* __restrict__ we2, const float* __restrict__ ae2,
                            const float* __restrict__ we3, const float* __restrict__ ae3,
                            const float* __restrict__ ea_sum,
                            float* __restrict__ vtab, float* __restrict__ lpae) {
    __shared__ int s_sum[1024];
    __shared__ float s_v[3][16];
    const int tid = threadIdx.x;
    int local[20];
    int run = 0;
    const int base = tid * 20;
    #pragma unroll
    for (int i = 0; i < 20; ++i) {
        int idx = base + i;
        int v = (idx < N_NODES) ? cnt[idx] : 0;
        run += v;
        local[i] = run;
    }
    s_sum[tid] = run;
    __syncthreads();
    for (int off = 1; off < 1024; off <<= 1) {
        int v = (tid >= off) ? s_sum[tid - off] : 0;
        __syncthreads();
        s_sum[tid] += v;
        __syncthreads();
    }
    const int prev = (tid > 0) ? s_sum[tid - 1] : 0;
    #pragma unroll
    for (int i = 0; i < 20; ++i) {
        int idx = base + i;
        if (idx < N_NODES) row_ptr[idx + 1] = prev + local[i];
    }
    if (tid == 0) row_ptr[0] = 0;

    // ---- vtab: 36 dot products (L0:16, L1:16, L2:4) ----
    if (tid < 36) {
        int L, k, h;
        const float* We; const float* Ae;
        if (tid < 16)      { L = 0; k = tid / 4;        h = tid & 3; We = we1; Ae = ae1; }
        else if (tid < 32) { L = 1; k = (tid - 16) / 4; h = tid & 3; We = we2; Ae = ae2; }
        else               { L = 2; k = tid - 32;       h = 0;       We = we3; Ae = ae3; }
        const int H = (L < 2) ? 4 : 1;
        float v = 0.f;
        for (int c = 0; c < 64; ++c) v += We[k * (H * 64) + h * 64 + c] * Ae[h * 64 + c];
        vtab[L * 16 + k * 4 + h] = v;
        s_v[L][k * 4 + h] = v;
    }
    __syncthreads();
    if (tid < 9) {
        int L = (tid < 4) ? 0 : ((tid < 8) ? 1 : 2);
        int h = (L == 0) ? tid : ((L == 1) ? tid - 4 : 0);
        const float inv = 1.0f / (float)N_EDGES;
        float l = 0.f;
        #pragma unroll
        for (int k = 0; k < 4; ++k) l += ea_sum[k] * inv * s_v[L][k * 4 + h];
        lpae[L * 4 + h] = l;
    }
}

// direct scatter: one packed 16B record {src, 4x fp16 ea} per edge
__global__ void scatter_kernel(const int* __restrict__ src, const int* __restrict__ dst,
                               const float* __restrict__ ea,
                               const int* __restrict__ row_ptr, int* __restrict__ cur,
                               int4* __restrict__ csr_edges) {
    int i = blockIdx.x * 256 + threadIdx.x;
    if (i < N_EDGES) {
        int d = dst[i];
        int p = atomicAdd(&cur[d], 1);
        int idx = row_ptr[d] + p;
        float4 e = ((const float4*)ea)[i];
        __half2 h01 = __floats2half2_rn(e.x, e.y);
        __half2 h23 = __floats2half2_rn(e.z, e.w);
        int4 r;
        r.x = src[i];
        r.y = *(int*)&h01;
        r.z = *(int*)&h23;
        r.w = 0;
        csr_edges[idx] = r;
    }
}

// ---------------- MFMA GEMM + fused attention scalars (K-step 64) ----------------
template<int N, int H>
__global__ __launch_bounds__(256) void mgemm_kernel(
    const __half* __restrict__ X, const __half* __restrict__ Wt,
    const float* __restrict__ asrc, const float* __restrict__ adst,
    __half* __restrict__ Y, float* __restrict__ a_s, float* __restrict__ a_d, int K) {
    constexpr int STR = 72;
    __shared__ _Float16 sX[64 * STR];
    __shared__ _Float16 sW[64 * STR];
    const int tid = threadIdx.x;
    const int lane = tid & 63, w = tid >> 6;
    const int l16 = lane & 15, kg = lane >> 4;
    const int n0 = blockIdx.x * 64;
    const int c0 = blockIdx.y * 64;
    const int by = blockIdx.y;

    floatx4 acc[4];
    #pragma unroll
    for (int ct = 0; ct < 4; ++ct) acc[ct] = (floatx4){0.f, 0.f, 0.f, 0.f};

    const int srow = tid >> 2, sseg = tid & 3;
    for (int k0 = 0; k0 < K; k0 += 64) {
        float4 xv0 = *(const float4*)(X + (size_t)(n0 + srow) * K + k0 + sseg * 8);
        float4 xv1 = *(const float4*)(X + (size_t)(n0 + srow) * K + k0 + 32 + sseg * 8);
        float4 wv0 = *(const float4*)(Wt + (size_t)(c0 + srow) * K + k0 + sseg * 8);
        float4 wv1 = *(const float4*)(Wt + (size_t)(c0 + srow) * K + k0 + 32 + sseg * 8);
        __syncthreads();
        *(float4*)&sX[srow * STR + sseg * 8] = xv0;
        *(float4*)&sX[srow * STR + 32 + sseg * 8] = xv1;
        *(float4*)&sW[srow * STR + sseg * 8] = wv0;
        *(float4*)&sW[srow * STR + 32 + sseg * 8] = wv1;
        __syncthreads();
        #pragma unroll
        for (int ks = 0; ks < 2; ++ks) {
            half8 a = *(const half8*)&sX[(w * 16 + l16) * STR + ks * 32 + kg * 8];
            #pragma unroll
            for (int ct = 0; ct < 4; ++ct) {
                half8 b = *(const half8*)&sW[(ct * 16 + l16) * STR + ks * 32 + kg * 8];
                acc[ct] = __builtin_amdgcn_mfma_f32_16x16x32_f16(a, b, acc[ct], 0, 0, 0);
            }
        }
    }

    // epilogue: C/D layout col = lane&15, row = (lane>>4)*4 + reg
    const int rowb = n0 + w * 16 + kg * 4;
    float ar[4], ad4[4];
    #pragma unroll
    for (int ct = 0; ct < 4; ++ct) {
        ar[ct] = asrc[c0 + ct * 16 + l16];
        ad4[ct] = adst[c0 + ct * 16 + l16];
    }
    #pragma unroll
    for (int ct = 0; ct < 4; ++ct) {
        const int col = c0 + ct * 16 + l16;
        #pragma unroll
        for (int r = 0; r < 4; ++r)
            Y[(size_t)(rowb + r) * N + col] = __float2half(acc[ct][r]);
    }
    #pragma unroll
    for (int r = 0; r < 4; ++r) {
        float p = acc[0][r] * ar[0] + acc[1][r] * ar[1] + acc[2][r] * ar[2] + acc[3][r] * ar[3];
        float q = acc[0][r] * ad4[0] + acc[1][r] * ad4[1] + acc[2][r] * ad4[2] + acc[3][r] * ad4[3];
        #pragma unroll
        for (int off = 1; off < 16; off <<= 1) {
            p += __shfl_xor(p, off, 64);
            q += __shfl_xor(q, off, 64);
        }
        if (l16 == 0) {
            const int node = rowb + r;
            a_s[(size_t)node * H + by] = p;
            a_d[(size_t)node * H + by] = q;
        }
    }
}

// ---------------- GAT aggregation: wave per node, self-shift softmax, packed edges ----------
template<int H, int HC, bool ELU>
__global__ __launch_bounds__(256) void agg5_kernel(
    const __half* __restrict__ hh,
    const float* __restrict__ a_s, const float* __restrict__ a_d,
    const float* __restrict__ vtab, const float* __restrict__ lpae,
    const int4* __restrict__ csr_edges,
    const int* __restrict__ row_ptr, const float* __restrict__ bias,
    __half* __restrict__ out) {
    constexpr int CPT = HC / 64;
    const int wave = threadIdx.x >> 6;
    const int lane = threadIdx.x & 63;
    const int d = blockIdx.x * 4 + wave;

    const int base = row_ptr[d], end = row_ptr[d + 1];
    const int colbase = lane * CPT;
    const int hl = (H == 1) ? 0 : (colbase >> 6);

    float vt[4][H];
    #pragma unroll
    for (int k = 0; k < 4; ++k)
        #pragma unroll
        for (int h = 0; h < H; ++h) vt[k][h] = vtab[k * 4 + h];

    float add_[H], lself[H];
    if (H == 4) {
        float4 t = *(const float4*)&a_d[(size_t)d * 4];
        add_[0] = t.x; add_[1] = t.y; add_[2] = t.z; add_[3] = t.w;
        float4 s4 = *(const float4*)&a_s[(size_t)d * 4];
        lself[0] = leaky02(s4.x + add_[0] + lpae[0]);
        lself[1] = leaky02(s4.y + add_[1] + lpae[1]);
        lself[2] = leaky02(s4.z + add_[2] + lpae[2]);
        lself[3] = leaky02(s4.w + add_[3] + lpae[3]);
    } else {
        add_[0] = a_d[d];
        lself[0] = leaky02(a_s[d] + add_[0] + lpae[0]);
    }

    // self-loop term: w_self = exp(lself - lself) = 1
    float zacc = 1.f;
    float acc[CPT];
    if (CPT == 4) {
        h4pack hv = *(const h4pack*)(hh + (size_t)d * HC + colbase);
        float2 f0 = __half22float2(hv.a);
        float2 f1 = __half22float2(hv.b);
        acc[0] = f0.x; acc[1] = f0.y; acc[2] = f1.x; acc[3] = f1.y;
    } else {
        acc[0] = __half2float(hh[(size_t)d * HC + colbase]);
    }

#define EDGE_STEP(tt) { \
        int s_ = __shfl(my_s, (tt), 64); \
        float w_; \
        if (H == 4) { \
            int t01 = __shfl(wp01, (tt), 64); \
            int t23 = __shfl(wp23, (tt), 64); \
            int selw = (hl < 2) ? t01 : t23; \
            __half2 hpw = *(__half2*)&selw; \
            float2 fw = __half22float2(hpw); \
            w_ = (hl & 1) ? fw.y : fw.x; \
        } else { \
            w_ = __shfl(w0, (tt), 64); \
        } \
        if (CPT == 4) { \
            h4pack hv_ = *(const h4pack*)(hh + (size_t)s_ * HC + colbase); \
            float2 f0_ = __half22float2(hv_.a); \
            float2 f1_ = __half22float2(hv_.b); \
            acc[0] += w_ * f0_.x; acc[1] += w_ * f0_.y; \
            acc[2] += w_ * f1_.x; acc[3] += w_ * f1_.y; \
        } else { \
            acc[0] += w_ * __half2float(hh[(size_t)s_ * HC + colbase]); \
        } \
        zacc += w_; }

    for (int c0 = base; c0 < end; c0 += 64) {
        const int nc = min(64, end - c0);
        int my_s = 0;
        int wp01 = 0, wp23 = 0;
        float w0 = 0.f;
        if (lane < nc) {
            int4 er = csr_edges[c0 + lane];
            my_s = er.x;
            __half2 h01 = *(__half2*)&er.y;
            __half2 h23 = *(__half2*)&er.z;
            float2 e01 = __half22float2(h01);
            float2 e23 = __half22float2(h23);
            if (H == 4) {
                float4 as4 = *(const float4*)&a_s[(size_t)my_s * 4];
                float l0 = leaky02(as4.x + add_[0] + e01.x * vt[0][0] + e01.y * vt[1][0] + e23.x * vt[2][0] + e23.y * vt[3][0]);
                float l1 = leaky02(as4.y + add_[1] + e01.x * vt[0][1] + e01.y * vt[1][1] + e23.x * vt[2][1] + e23.y * vt[3][1]);
                float l2 = leaky02(as4.z + add_[2] + e01.x * vt[0][2] + e01.y * vt[1][2] + e23.x * vt[2][2] + e23.y * vt[3][2]);
                float l3 = leaky02(as4.w + add_[3] + e01.x * vt[0][3] + e01.y * vt[1][3] + e23.x * vt[2][3] + e23.y * vt[3][3]);
                __half2 p01 = __floats2half2_rn(__expf(l0 - lself[0]), __expf(l1 - lself[1]));
                __half2 p23 = __floats2half2_rn(__expf(l2 - lself[2]), __expf(l3 - lself[3]));
                wp01 = *(int*)&p01;
                wp23 = *(int*)&p23;
            } else {
                float l0 = leaky02(a_s[my_s] + add_[0] + e01.x * vt[0][0] + e01.y * vt[1][0] + e23.x * vt[2][0] + e23.y * vt[3][0]);
                w0 = __expf(l0 - lself[0]);
            }
        }
        int t = 0;
        for (; t + 8 <= nc; t += 8) {
            EDGE_STEP(t)
            EDGE_STEP(t + 1)
            EDGE_STEP(t + 2)
            EDGE_STEP(t + 3)
            EDGE_STEP(t + 4)
            EDGE_STEP(t + 5)
            EDGE_STEP(t + 6)
            EDGE_STEP(t + 7)
        }
        for (; t < nc; ++t) {
            EDGE_STEP(t)
        }
    }
#undef EDGE_STEP

    const float invz = 1.f / (zacc + 1e-16f);
    #pragma unroll
    for (int c = 0; c < CPT; ++c) {
        float v = acc[c] * invz + bias[colbase + c];
        if (ELU) v = (v > 0.f) ? v : (__expf(v) - 1.f);
        acc[c] = v;
    }
    if (CPT == 4) {
        __half2* op = (__half2*)(out + (size_t)d * HC + colbase);
        op[0] = __floats2half2_rn(acc[0], acc[1]);
        op[1] = __floats2half2_rn(acc[2], acc[3]);
    } else {
        out[(size_t)d * HC + colbase] = __float2half(acc[0]);
    }
}

// ---------------- global mean pool (hierarchical, fp16 in) ----------------
__global__ void pool_kernel(const __half* __restrict__ h3, const int* __restrict__ batch,
                            float* __restrict__ psum, float* __restrict__ pcnt) {
    __shared__ float s_acc[8][64];
    __shared__ float s_cnt[8];
    const int tid = threadIdx.x; // 256
    for (int i = tid; i < 512; i += 256) s_acc[i >> 6][i & 63] = 0.f;
    if (tid < 8) s_cnt[tid] = 0.f;
    __syncthreads();
    const int col = tid & 63, nl = tid >> 6;
    const int n0 = blockIdx.x * 64;
    for (int nn = nl; nn < 64; nn += 4) {
        int n = n0 + nn;
        if (n < N_NODES) {
            int b = batch[n];
            atomicAdd(&s_acc[b][col], __half2float(h3[(size_t)n * 64 + col]));
            if (col == 0) atomicAdd(&s_cnt[b], 1.0f);
        }
    }
    __syncthreads();
    for (int i = tid; i < 512; i += 256) {
        float v = s_acc[i >> 6][i & 63];
        if (v != 0.f) atomicAdd(&psum[i], v);
    }
    if (tid < 8 && s_cnt[tid] > 0.f) atomicAdd(&pcnt[tid], s_cnt[tid]);
}

// ---------------- fused head: g -> p1 -> static_features -> scores (block = graph) --------
__global__ void head_kernel(const float* __restrict__ psum, const float* __restrict__ pcnt,
                            const float* __restrict__ w1, const float* __restrict__ b1,
                            const float* __restrict__ w2, const float* __restrict__ b2,
                            const float* __restrict__ vw, const float* __restrict__ vb,
                            float* __restrict__ out) {
    const int b = blockIdx.x;
    const int tid = threadIdx.x; // 768
    const int wave = tid >> 6, lane = tid & 63;
    __shared__ float s_g[64];
    __shared__ float s_p1[128];
    __shared__ float s_red[12][5];
    if (tid < 64) {
        float c = pcnt[b];
        c = (c < 1.f) ? 1.f : c;
        s_g[tid] = psum[b * 64 + tid] / c;
    }
    __syncthreads();
    if (tid < 128) {
        float a = b1[tid];
        #pragma unroll 8
        for (int k = 0; k < 64; ++k) a += s_g[k] * w1[k * 128 + tid];
        s_p1[tid] = fmaxf(a, 0.f);
    }
    __syncthreads();
    float a = b2[tid];
    #pragma unroll 8
    for (int k = 0; k < 128; ++k) a += s_p1[k] * w2[k * 768 + tid];
    out[b * 768 + tid] = a;

    float part[5];
    #pragma unroll
    for (int v = 0; v < 5; ++v) part[v] = a * vw[tid * 5 + v];
    #pragma unroll
    for (int v = 0; v < 5; ++v)
        #pragma unroll
        for (int off = 32; off; off >>= 1) part[v] += __shfl_down(part[v], off, 64);
    if (lane == 0) {
        #pragma unroll
        for (int v = 0; v < 5; ++v) s_red[wave][v] = part[v];
    }
    __syncthreads();
    if (tid < 5) {
        float acc = vb[tid];
        #pragma unroll
        for (int w = 0; w < 12; ++w) acc += s_red[w][tid];
        out[6144 + b * 5 + tid] = 1.f / (1.f + __expf(-acc));
    }
}

extern "C" void kernel_launch(void* const* d_in, const int* in_sizes, int n_in,
                              void* d_out, int out_size, void* d_ws, size_t ws_size,
                              hipStream_t stream) {
    const float* x       = (const float*)d_in[0];
    const int*   eidx    = (const int*)d_in[1];
    const float* ea      = (const float*)d_in[2];
    const int*   batch   = (const int*)d_in[3];
    const float* enc_w1  = (const float*)d_in[4];
    const float* enc_b1  = (const float*)d_in[5];
    const float* enc_w2  = (const float*)d_in[6];
    const float* enc_b2  = (const float*)d_in[7];
    const float* g1_w    = (const float*)d_in[8];
    const float* g1_asrc = (const float*)d_in[9];
    const float* g1_adst = (const float*)d_in[10];
    const float* g1_we   = (const float*)d_in[11];
    const float* g1_ae   = (const float*)d_in[12];
    const float* g1_b    = (const float*)d_in[13];
    const float* g2_w    = (const float*)d_in[14];
    const float* g2_asrc = (const float*)d_in[15];
    const float* g2_adst = (const float*)d_in[16];
    const float* g2_we   = (const float*)d_in[17];
    const float* g2_ae   = (const float*)d_in[18];
    const float* g2_b    = (const float*)d_in[19];
    const float* g3_w    = (const float*)d_in[20];
    const float* g3_asrc = (const float*)d_in[21];
    const float* g3_adst = (const float*)d_in[22];
    const float* g3_we   = (const float*)d_in[23];
    const float* g3_ae   = (const float*)d_in[24];
    const float* g3_b    = (const float*)d_in[25];
    const float* pw1     = (const float*)d_in[26];
    const float* pb1     = (const float*)d_in[27];
    const float* pw2     = (const float*)d_in[28];
    const float* pb2     = (const float*)d_in[29];
    const float* vw      = (const float*)d_in[30];
    const float* vb      = (const float*)d_in[31];

    const int* src = eidx;
    const int* dst = eidx + N_EDGES;

    // ---- workspace layout ----
    __half* h16a = (__half*)d_ws;                           // [M_PAD][256] f16
    __half* h16b = h16a + (size_t)M_PAD * 256;              // [M_PAD][256] f16
    __half* hh16 = h16b + (size_t)M_PAD * 256;              // [M_PAD][256] f16
    __half* wt1  = hh16 + (size_t)M_PAD * 256;              // [256][128]
    __half* wt2  = wt1 + 32768;                             // [256][256]
    __half* wt3  = wt2 + 65536;                             // [64][256]
    float* asb   = (float*)(wt3 + 16384);                   // [M_PAD][4]
    float* adb   = asb + (size_t)M_PAD * 4;                 // [M_PAD][4]
    float* zreg  = adb + (size_t)M_PAD * 4;
    float* ea_sum = zreg;                                   // 4
    float* psum   = zreg + 4;                               // 512
    float* pcnt   = zreg + 516;                             // 8
    float* vtab   = zreg + 524;                             // 3*16
    float* lpae   = zreg + 572;                             // 3*4
    int* icnt    = (int*)(zreg + 584);                      // N
    int* icur    = icnt + N_NODES;                          // N
    int* irow    = icur + N_NODES;                          // N+16
    int4* csr_edges = (int4*)(irow + N_NODES + 16);         // E x 16B (16B aligned)

    // one memset covers zreg (584 floats) + icnt + icur (2N ints), contiguous
    hipMemsetAsync(zreg, 0, (584 + 2 * N_NODES) * sizeof(float), stream);

    fused_prep_kernel<<<1954, 256, 0, stream>>>(ea, dst, ea_sum, icnt,
                                                g1_w, g2_w, g3_w, wt1, wt2, wt3,
                                                x, enc_w1, enc_b1, enc_w2, enc_b2, h16a);
    scan_kernel<<<1, 1024, 0, stream>>>(icnt, irow,
                                        g1_we, g1_ae, g2_we, g2_ae, g3_we, g3_ae,
                                        ea_sum, vtab, lpae);
    scatter_kernel<<<(N_EDGES + 255) / 256, 256, 0, stream>>>(src, dst, ea, irow, icur, csr_edges);

    // layer 1: K=128 -> HC=256, H=4, ELU      (h16a -> hh16 -> h16b)
    mgemm_kernel<256, 4><<<dim3(M_PAD / 64, 4), 256, 0, stream>>>(h16a, wt1, g1_asrc, g1_adst, hh16, asb, adb, 128);
    agg5_kernel<4, 256, true><<<N_NODES / 4, 256, 0, stream>>>(hh16, asb, adb, vtab, lpae, csr_edges, irow, g1_b, h16b);

    // layer 2: K=256 -> HC=256, H=4, ELU      (h16b -> hh16 -> h16a)
    mgemm_kernel<256, 4><<<dim3(M_PAD / 64, 4), 256, 0, stream>>>(h16b, wt2, g2_asrc, g2_adst, hh16, asb, adb, 256);
    agg5_kernel<4, 256, true><<<N_NODES / 4, 256, 0, stream>>>(hh16, asb, adb, vtab + 16, lpae + 4, csr_edges, irow, g2_b, h16a);

    // layer 3: K=256 -> HC=64, H=1, no ELU    (h16a -> hh16 -> h16b)
    mgemm_kernel<64, 1><<<dim3(M_PAD / 64, 1), 256, 0, stream>>>(h16a, wt3, g3_asrc, g3_adst, hh16, asb, adb, 256);
    agg5_kernel<1, 64, false><<<N_NODES / 4, 256, 0, stream>>>(hh16, asb, adb, vtab + 32, lpae + 8, csr_edges, irow, g3_b, h16b);

    pool_kernel<<<(N_NODES + 63) / 64, 256, 0, stream>>>(h16b, batch, psum, pcnt);
    head_kernel<<<8, 768, 0, stream>>>(psum, pcnt, pw1, pb1, pw2, pb2, vw, vb, (float*)d_out);
}